// Round 3
// baseline (202.559 us; speedup 1.0000x reference)
//
#include <hip/hip_runtime.h>

typedef unsigned short ushort;
typedef unsigned int uint;

constexpr int B = 2, C = 64, H = 112, W = 112;
constexpr int HW = H * W;          // 12544
constexpr int NPIX = B * HW;       // 25088
constexpr int NBLK = 392;          // 8 patches x 49 tiles
constexpr float EPS_LN = 1e-6f, EPS_NORM = 1e-7f;

__device__ __forceinline__ float rcp_fast(float x) { return __builtin_amdgcn_rcpf(x); }
__device__ __forceinline__ float sigmoid_f(float x) { return rcp_fast(1.f + __expf(-x)); }
// Force wave-uniformity so the compiler emits s_load for weight rows.
__device__ __forceinline__ int uni(int x) { return __builtin_amdgcn_readfirstlane(x); }

// f32 -> bf16 bits (round-nearest-even) + pair pack/unpack.
__device__ __forceinline__ ushort rne16(float x) {
    uint u = __float_as_uint(x);
    u += 0x7fffu + ((u >> 16) & 1u);
    return (ushort)(u >> 16);
}
__device__ __forceinline__ uint pack2(float a, float b) {
    return (uint)rne16(a) | ((uint)rne16(b) << 16);
}
__device__ __forceinline__ float2 up2(uint u) {
    return make_float2(__uint_as_float(u << 16), __uint_as_float(u & 0xffff0000u));
}

// XCD-patch swizzle (BOTH kernels -> producer/consumer share an XCD L2):
// blk&7 -> (image, quadrant); blk>>3 -> tile in the 7x7-tile patch.
__device__ __forceinline__ void decode_blk(int blk, int& b, int& ty, int& tx) {
    int p8 = blk & 7, i = blk >> 3;
    b = p8 >> 2;
    int quad = p8 & 3;
    int lty = i / 7, ltx = i - lty * 7;
    ty = (quad >> 1) * 7 + lty;
    tx = (quad & 1) * 7 + ltx;
}

// ---------------------------------------------------------------------------
// k1: px = range_proj(semantic) -> px16[p][64] (bf16) + sqnorm[p].
// 8 waves x 8 outputs, 512 threads. Register peak capped ~50 by splitting
// both 64-deep dots into two 32-half passes with 8 per-wave accumulators
// (rounds 1-2: allocator pinned 64 VGPRs at 512 thr and spilled ~50/thread;
// launch_bounds(512,2) gives budget >=128 under either arg semantics, and
// the half-pass structure fits even a 64 budget).
// ---------------------------------------------------------------------------
__global__ void __launch_bounds__(512, 2)
k1_range_proj(
    const float* __restrict__ sem,
    const float* __restrict__ w1, const float* __restrict__ b1,
    const float* __restrict__ g,  const float* __restrict__ be,
    const float* __restrict__ w2, const float* __restrict__ b2,
    ushort* __restrict__ px16, float* __restrict__ sqnorm)
{
    __shared__ float f_scr[64 * 64];    // [o][pix]
    __shared__ float t_scr[64 * 65];    // [o][pix] pitch 65 (transpose buffer)
    __shared__ float pm[8 * 64], ps[8 * 64], p2s[8 * 64];

    const int tid = threadIdx.x, lane = tid & 63, wv = tid >> 6;   // wv 0..7
    int b, ty, tx; decode_blk(blockIdx.x, b, ty, tx);
    const int h = ty * 8 + (lane >> 3), w = tx * 8 + (lane & 7);
    const int hw = h * W + w;

    const int o0 = uni(wv * 8);

    // ---- conv1: two 32-half passes, facc[8] per-wave accumulators ----
    float facc[8];
#pragma unroll
    for (int j = 0; j < 8; ++j) facc[j] = b1[o0 + j];
    {
        float svh[32];
#pragma unroll
        for (int k = 0; k < 32; ++k) svh[k] = sem[(size_t)(b * 64 + k) * HW + hw];
#pragma unroll
        for (int j = 0; j < 8; ++j) {
            const float* wr = &w1[(o0 + j) * 64];
            float a0 = 0, a1 = 0, a2 = 0, a3 = 0;
#pragma unroll
            for (int k = 0; k < 32; k += 4) {
                a0 += wr[k] * svh[k];       a1 += wr[k + 1] * svh[k + 1];
                a2 += wr[k + 2] * svh[k + 2]; a3 += wr[k + 3] * svh[k + 3];
            }
            facc[j] += (a0 + a1) + (a2 + a3);
        }
    }
    float macc = 0.f, sacc = 0.f;
    {
        float svh[32];
#pragma unroll
        for (int k = 0; k < 32; ++k) svh[k] = sem[(size_t)(b * 64 + 32 + k) * HW + hw];
#pragma unroll
        for (int j = 0; j < 8; ++j) {
            const float* wr = &w1[(o0 + j) * 64 + 32];
            float a0 = 0, a1 = 0, a2 = 0, a3 = 0;
#pragma unroll
            for (int k = 0; k < 32; k += 4) {
                a0 += wr[k] * svh[k];       a1 += wr[k + 1] * svh[k + 1];
                a2 += wr[k + 2] * svh[k + 2]; a3 += wr[k + 3] * svh[k + 3];
            }
            float f = facc[j] + (a0 + a1) + (a2 + a3);
            f_scr[(o0 + j) * 64 + lane] = f;   // bank=lane%32: 2-way, free
            macc += f; sacc += f * f;
        }
    }
    pm[wv * 64 + lane] = macc; ps[wv * 64 + lane] = sacc;
    __syncthreads();
    float m = 0.f, va = 0.f;
#pragma unroll
    for (int w8 = 0; w8 < 8; ++w8) { m += pm[w8 * 64 + lane]; va += ps[w8 * 64 + lane]; }
    m *= (1.f / 64.f);
    va = va * (1.f / 64.f) - m * m;
    float rstd = rsqrtf(va + EPS_LN);

    // ---- conv2: two 32-half passes over LN+SiLU values ----
    float zacc[8];
#pragma unroll
    for (int j = 0; j < 8; ++j) zacc[j] = b2[o0 + j];
    {
        float sh[32];
#pragma unroll
        for (int k = 0; k < 32; ++k) {
            float y = g[k] * (f_scr[k * 64 + lane] - m) * rstd + be[k];
            sh[k] = y * sigmoid_f(y);
        }
#pragma unroll
        for (int j = 0; j < 8; ++j) {
            const float* wr = &w2[(o0 + j) * 64];
            float a0 = 0, a1 = 0, a2 = 0, a3 = 0;
#pragma unroll
            for (int k = 0; k < 32; k += 4) {
                a0 += wr[k] * sh[k];       a1 += wr[k + 1] * sh[k + 1];
                a2 += wr[k + 2] * sh[k + 2]; a3 += wr[k + 3] * sh[k + 3];
            }
            zacc[j] += (a0 + a1) + (a2 + a3);
        }
    }
    float sq = 0.f;
    {
        float sh[32];
#pragma unroll
        for (int k = 0; k < 32; ++k) {
            float y = g[32 + k] * (f_scr[(32 + k) * 64 + lane] - m) * rstd + be[32 + k];
            sh[k] = y * sigmoid_f(y);
        }
#pragma unroll
        for (int j = 0; j < 8; ++j) {
            const float* wr = &w2[(o0 + j) * 64 + 32];
            float a0 = 0, a1 = 0, a2 = 0, a3 = 0;
#pragma unroll
            for (int k = 0; k < 32; k += 4) {
                a0 += wr[k] * sh[k];       a1 += wr[k + 1] * sh[k + 1];
                a2 += wr[k + 2] * sh[k + 2]; a3 += wr[k + 3] * sh[k + 3];
            }
            float z = zacc[j] + (a0 + a1) + (a2 + a3);
            t_scr[(o0 + j) * 65 + lane] = z;   // bank=(o+lane)%32: conflict-free
            sq += z * z;                       // sqnorm from f32 z
        }
    }
    p2s[wv * 64 + lane] = sq;
    __syncthreads();
    if (wv == 0) {
        float t = 0.f;
#pragma unroll
        for (int w8 = 0; w8 < 8; ++w8) t += p2s[w8 * 64 + lane];
        sqnorm[(size_t)b * HW + hw] = t;
    }
    // transpose-out: wave wv stores pixels o0..o0+7 (128-B bf16 rows)
    for (int j = 0; j < 8; ++j) {
        int ii = o0 + j;
        int hwi = (ty * 8 + (ii >> 3)) * W + tx * 8 + (ii & 7);
        px16[((size_t)b * HW + hwi) * 64 + lane] = rne16(t_scr[lane * 65 + ii]);
    }
}

// ---------------------------------------------------------------------------
// k23: bilateral weights + gated fixup + normalize + neighborhood reduction +
// output_proj. 512 threads (8 waves) / 8x8 tile. LDS arena 76048 B -> 2
// blocks/CU. Register-pressure-shaped for the 512-thr allocator: no entry sv
// prefetch; fixup conv1 split into comb-pass + two sem-half passes with
// partials accumulated in fscr (LDS). Kernel peak ~80 VGPRs (P2's cv[64]).
// bf16 halo row r = 128 B = 8 chunks of 16 B; chunk q stored at q^(r&7).
// ---------------------------------------------------------------------------
__global__ void __launch_bounds__(512, 2)
k23_fused(
    const ushort* __restrict__ px16, const float* __restrict__ sqnorm,
    const float* __restrict__ sem,  const float* __restrict__ spat,
    const float* __restrict__ fw1, const float* __restrict__ fb1,
    const float* __restrict__ fg,  const float* __restrict__ fbe,
    const float* __restrict__ fw2, const float* __restrict__ fb2,
    const float* __restrict__ w1, const float* __restrict__ b1,
    const float* __restrict__ g,  const float* __restrict__ be,
    const float* __restrict__ w2, const float* __restrict__ b2,
    const float* __restrict__ sigma_, float* __restrict__ out)
{
    __shared__ __align__(16) float smem[19012];          // 76048 B arena
    ushort* haloA = (ushort*)smem;                       // px halo (bf16), floats 0..6272
    ushort* haloB = (ushort*)(smem + 6272);              // spat halo (bf16), floats 6272..12544
    float*  comb  = smem + 12544;                        // 49x64 -> ..15680
    float*  fscr  = smem + 15680;                        // 49x64 -> ..18816
    float*  sqn_l = smem + 18816;                        // 196   -> ..19012
    // Phase-local overlays on dead regions:
    //  P3 (haloA dead after P2):
    float*  pm3 = smem;                                  // 512
    float*  ps3 = smem + 512;                            // 512
    float*  pt  = smem + 1024;                           // 512
    //  P6 (haloA + haloB dead after P5):
    float*  av  = smem;                                  // 64x64 f32
    float*  f2  = smem + 6272;                           // 64x64 f32
    float*  pm6 = smem + 4096;                           // 512
    float*  ps6 = smem + 4608;                           // 512 (ends 5120 < 6272)

    const int tid = threadIdx.x, lane = tid & 63, wv = tid >> 6;   // wv 0..7
    int b, ty, tx; decode_blk(blockIdx.x, b, ty, tx);
    const int h = ty * 8 + (lane >> 3), w = tx * 8 + (lane & 7);
    const int hw = h * W + w;
    const int h0 = ty * 8 - 3, w0 = tx * 8 - 3;

    // ---- P4 (hoisted): stage spat halo -> haloB (bf16), 2 threads/halo-pix ----
    {
        const int r = tid >> 1, hf = tid & 1;
        if (r < 196) {
            const int ry = (r * 2341) >> 15, rx = r - ry * 14;   // exact /14 for r<256
            const int hh = h0 + ry, ww = w0 + rx;
            const bool valid = (unsigned)hh < (unsigned)H && (unsigned)ww < (unsigned)W;
            const int soff = hh * W + ww;
            const int rsw = (r & 7), rb_ = r << 6;
#pragma unroll
            for (int cq = 0; cq < 4; ++cq) {
                const int q = hf * 4 + cq;
                uint4 v = make_uint4(0u, 0u, 0u, 0u);
                if (valid) {
                    const float* sp = &spat[(size_t)(b * 64 + 8 * q) * HW + soff];
                    v.x = pack2(sp[0],      sp[HW]);
                    v.y = pack2(sp[2 * HW], sp[3 * HW]);
                    v.z = pack2(sp[4 * HW], sp[5 * HW]);
                    v.w = pack2(sp[6 * HW], sp[7 * HW]);
                }
                *(uint4*)&haloB[rb_ + ((q ^ rsw) << 3)] = v;
            }
        }
    }

    // ---- P1: stage px halo -> haloA (bf16): 1568 16-B loads over 512 thr ----
    for (int i = 0; i < 4; ++i) {
        int idx = i * 512 + tid;
        if (idx < 1568) {
            int r = idx >> 3, q = idx & 7;
            int ry = (r * 2341) >> 15, rx = r - ry * 14;     // exact /14 for r<256
            int hh = h0 + ry, ww = w0 + rx;
            bool valid = (unsigned)hh < (unsigned)H && (unsigned)ww < (unsigned)W;
            uint4 v = make_uint4(0u, 0u, 0u, 0u);
            if (valid) v = *(const uint4*)&px16[((size_t)b * HW + hh * W + ww) * 64 + 8 * q];
            *(uint4*)&haloA[(r << 6) + ((q ^ (r & 7)) << 3)] = v;
        }
    }
    if (tid < 196) {
        int ry = (tid * 2341) >> 15, rx = tid - ry * 14;
        int hh = h0 + ry, ww = w0 + rx;
        bool valid = (unsigned)hh < (unsigned)H && (unsigned)ww < (unsigned)W;
        float v = 0.f;
        if (valid) v = sqnorm[(size_t)b * HW + hh * W + ww];
        sqn_l[tid] = v;
    }
    __syncthreads();

    // ---- P2: bilateral weights, neighbors split across 8 waves ----
    const int rbase = (lane >> 3) * 14 + (lane & 7);
    const int rp = rbase + 45;
    {
        float cv[64];
#pragma unroll
        for (int q = 0; q < 8; ++q) {
            uint4 v = *(const uint4*)&haloA[(rp << 6) + ((q ^ (rp & 7)) << 3)];
            float2 p0_ = up2(v.x), p1_ = up2(v.y), p2_ = up2(v.z), p3_ = up2(v.w);
            cv[8 * q + 0] = p0_.x; cv[8 * q + 1] = p0_.y;
            cv[8 * q + 2] = p1_.x; cv[8 * q + 3] = p1_.y;
            cv[8 * q + 4] = p2_.x; cv[8 * q + 5] = p2_.y;
            cv[8 * q + 6] = p3_.x; cv[8 * q + 7] = p3_.y;
        }
        const float sqc = sqn_l[rp];
        const float sg_ = sigma_[0];
        const float inv2s2 = rcp_fast(2.f * sg_ * sg_);
        for (int i = 0; i < 7; ++i) {
            int n = uni(wv + 8 * i);
            if (n < 49) {
                int ryn = n / 7, rxn = n - ryn * 7;
                int dy = ryn - 3, dx = rxn - 3;
                int rn = rbase + ryn * 14 + rxn;
                float d0 = 0, d1 = 0, d2 = 0, d3 = 0;
#pragma unroll
                for (int q = 0; q < 8; ++q) {
                    uint4 v = *(const uint4*)&haloA[(rn << 6) + ((q ^ (rn & 7)) << 3)];
                    float2 a = up2(v.x), bb = up2(v.y), c = up2(v.z), d = up2(v.w);
                    d0 += a.x  * cv[8 * q + 0]; d1 += a.y  * cv[8 * q + 1];
                    d2 += bb.x * cv[8 * q + 2]; d3 += bb.y * cv[8 * q + 3];
                    d0 += c.x  * cv[8 * q + 4]; d1 += c.y  * cv[8 * q + 5];
                    d2 += d.x  * cv[8 * q + 6]; d3 += d.y  * cv[8 * q + 7];
                }
                float dot = (d0 + d1) + (d2 + d3);
                float dist2 = fmaxf(sqn_l[rn] + sqc - 2.f * dot, 0.f);
                bool validn = (unsigned)(h + dy) < (unsigned)H && (unsigned)(w + dx) < (unsigned)W;
                float d2n = (float)(dy * dy + dx * dx);
                comb[n * 64 + lane] = validn ? __expf(-(dist2 * (1.f / 128.f) + d2n * inv2s2)) : 0.f;
            }
        }
    }
    __syncthreads();   // px-halo reads + comb writes done (haloA dead below)

    // ---- P3: gated fixup. conv1 split: comb-pass, then two sem-half passes
    //      with partials in fscr (own rows -> no race, barrier before LN) ----
    {
        float cb[49];
#pragma unroll
        for (int n = 0; n < 49; ++n) cb[n] = comb[n * 64 + lane];
        for (int i = 0; i < 7; ++i) {
            const int o = uni(wv + 8 * i);   // uniform -> s_load weight row
            if (o < 49) {
                const float* wr = &fw1[o * 113];
                float a0 = 0, a1 = 0, a2 = 0, a3 = 0;
#pragma unroll
                for (int k = 0; k < 48; k += 4) {
                    a0 += wr[k] * cb[k];       a1 += wr[k + 1] * cb[k + 1];
                    a2 += wr[k + 2] * cb[k + 2]; a3 += wr[k + 3] * cb[k + 3];
                }
                a0 += wr[48] * cb[48];
                fscr[o * 64 + lane] = (a0 + a1) + (a2 + a3) + fb1[o];
            }
        }
    }
    {
        float svh[32];
#pragma unroll
        for (int k = 0; k < 32; ++k) svh[k] = sem[(size_t)(b * 64 + k) * HW + hw];
        for (int i = 0; i < 7; ++i) {
            const int o = uni(wv + 8 * i);
            if (o < 49) {
                const float* wr2 = &fw1[o * 113 + 49];
                float a0 = 0, a1 = 0, a2 = 0, a3 = 0;
#pragma unroll
                for (int k = 0; k < 32; k += 4) {
                    a0 += wr2[k] * svh[k];       a1 += wr2[k + 1] * svh[k + 1];
                    a2 += wr2[k + 2] * svh[k + 2]; a3 += wr2[k + 3] * svh[k + 3];
                }
                fscr[o * 64 + lane] += (a0 + a1) + (a2 + a3);
            }
        }
    }
    float macc = 0.f, sacc = 0.f;
    {
        float svh[32];
#pragma unroll
        for (int k = 0; k < 32; ++k) svh[k] = sem[(size_t)(b * 64 + 32 + k) * HW + hw];
        for (int i = 0; i < 7; ++i) {
            const int o = uni(wv + 8 * i);
            if (o < 49) {
                const float* wr2 = &fw1[o * 113 + 81];   // 49 + 32
                float a0 = 0, a1 = 0, a2 = 0, a3 = 0;
#pragma unroll
                for (int k = 0; k < 32; k += 4) {
                    a0 += wr2[k] * svh[k];       a1 += wr2[k + 1] * svh[k + 1];
                    a2 += wr2[k + 2] * svh[k + 2]; a3 += wr2[k + 3] * svh[k + 3];
                }
                float f = fscr[o * 64 + lane] + (a0 + a1) + (a2 + a3);
                fscr[o * 64 + lane] = f;
                macc += f; sacc += f * f;
            }
        }
    }
    pm3[wv * 64 + lane] = macc; ps3[wv * 64 + lane] = sacc;
    __syncthreads();
    {
        float m = 0.f, va = 0.f;
#pragma unroll
        for (int w8 = 0; w8 < 8; ++w8) { m += pm3[w8 * 64 + lane]; va += ps3[w8 * 64 + lane]; }
        m *= (1.f / 49.f);
        va = va * (1.f / 49.f) - m * m;
        float rstd = rsqrtf(va + EPS_LN);
        float s[49];
#pragma unroll
        for (int k = 0; k < 49; ++k) {
            float y = fg[k] * (fscr[k * 64 + lane] - m) * rstd + fbe[k];
            s[k] = y * sigmoid_f(y);
        }
        float tacc = 0.f;
        for (int i = 0; i < 7; ++i) {
            const int o = uni(wv + 8 * i);
            if (o < 49) {
                const float* wr = &fw2[o * 49];
                float a0 = 0, a1 = 0, a2 = 0, a3 = 0;
#pragma unroll
                for (int k = 0; k < 48; k += 4) {
                    a0 += wr[k] * s[k];       a1 += wr[k + 1] * s[k + 1];
                    a2 += wr[k + 2] * s[k + 2]; a3 += wr[k + 3] * s[k + 3];
                }
                a0 += wr[48] * s[48];
                float fo = (a0 + a1) + (a2 + a3) + fb2[o];
                float gate = 1.f + sigmoid_f(fo);
                float cx = comb[o * 64 + lane] * gate;   // own rows: no race
                comb[o * 64 + lane] = cx;
                tacc += cx;
            }
        }
        pt[wv * 64 + lane] = tacc;
    }
    __syncthreads();
    float tsum = EPS_NORM;
#pragma unroll
    for (int w8 = 0; w8 < 8; ++w8) tsum += pt[w8 * 64 + lane];
    const float inv = rcp_fast(tsum);

    // ---- P5: weighted neighborhood reduction (haloB, staged at entry) ----
    const int c0 = uni(wv * 8);
    const int qq = c0 >> 3;             // wave's single 8-ch chunk
    float acc[8];
#pragma unroll
    for (int j = 0; j < 8; ++j) acc[j] = 0.f;
    for (int n = 0; n < 49; ++n) {
        int ryn = n / 7, rxn = n - ryn * 7;
        int rn = rbase + ryn * 14 + rxn;
        float cn = comb[n * 64 + lane] * inv;
        uint4 v = *(const uint4*)&haloB[(rn << 6) + ((qq ^ (rn & 7)) << 3)];
        float2 a = up2(v.x), bb = up2(v.y), c = up2(v.z), d = up2(v.w);
        acc[0] += cn * a.x;  acc[1] += cn * a.y;
        acc[2] += cn * bb.x; acc[3] += cn * bb.y;
        acc[4] += cn * c.x;  acc[5] += cn * c.y;
        acc[6] += cn * d.x;  acc[7] += cn * d.y;
    }
    __syncthreads();   // haloA/haloB/comb reads done -> av/f2 overlays safe

    // ---- P6: output_proj (f32 overlays on the two dead halo regions) ----
    for (int j = 0; j < 8; ++j) av[(c0 + j) * 64 + lane] = acc[j];
    __syncthreads();
    float xv[64];
#pragma unroll
    for (int k = 0; k < 64; ++k) xv[k] = av[k * 64 + lane];
    float macc2 = 0.f, sacc2 = 0.f;
#pragma unroll
    for (int j = 0; j < 8; ++j) {
        const int o = c0 + j;             // uniform
        const float* wr = &w1[o * 64];
        float a0 = 0, a1 = 0, a2 = 0, a3 = 0;
#pragma unroll
        for (int k = 0; k < 64; k += 4) {
            a0 += wr[k] * xv[k];       a1 += wr[k + 1] * xv[k + 1];
            a2 += wr[k + 2] * xv[k + 2]; a3 += wr[k + 3] * xv[k + 3];
        }
        float f = (a0 + a1) + (a2 + a3) + b1[o];
        f2[o * 64 + lane] = f;
        macc2 += f; sacc2 += f * f;
    }
    pm6[wv * 64 + lane] = macc2; ps6[wv * 64 + lane] = sacc2;
    __syncthreads();
    float m = 0.f, va = 0.f;
#pragma unroll
    for (int w8 = 0; w8 < 8; ++w8) { m += pm6[w8 * 64 + lane]; va += ps6[w8 * 64 + lane]; }
    m *= (1.f / 64.f);
    va = va * (1.f / 64.f) - m * m;
    float rstd = rsqrtf(va + EPS_LN);
    float yv[64];
#pragma unroll
    for (int k = 0; k < 64; ++k)
        yv[k] = g[k] * (f2[k * 64 + lane] - m) * rstd + be[k];
#pragma unroll
    for (int j = 0; j < 8; ++j) {
        const int o = c0 + j;             // uniform
        const float* wr = &w2[o * 64];
        float a0 = 0, a1 = 0, a2 = 0, a3 = 0;
#pragma unroll
        for (int k = 0; k < 64; k += 4) {
            a0 += wr[k] * yv[k];       a1 += wr[k + 1] * yv[k + 1];
            a2 += wr[k + 2] * yv[k + 2]; a3 += wr[k + 3] * yv[k + 3];
        }
        float z = (a0 + a1) + (a2 + a3) + b2[o];
        out[(size_t)(b * 64 + o) * HW + hw] = z;
    }
}

extern "C" void kernel_launch(void* const* d_in, const int* in_sizes, int n_in,
                              void* d_out, int out_size, void* d_ws, size_t ws_size,
                              hipStream_t stream)
{
    const float* spatial  = (const float*)d_in[0];
    const float* semantic = (const float*)d_in[1];
    const float* rp_w1 = (const float*)d_in[2];
    const float* rp_b1 = (const float*)d_in[3];
    const float* rp_g  = (const float*)d_in[4];
    const float* rp_be = (const float*)d_in[5];
    const float* rp_w2 = (const float*)d_in[6];
    const float* rp_b2 = (const float*)d_in[7];
    const float* fx_w1 = (const float*)d_in[8];
    const float* fx_b1 = (const float*)d_in[9];
    const float* fx_g  = (const float*)d_in[10];
    const float* fx_be = (const float*)d_in[11];
    const float* fx_w2 = (const float*)d_in[12];
    const float* fx_b2 = (const float*)d_in[13];
    const float* op_w1 = (const float*)d_in[14];
    const float* op_b1 = (const float*)d_in[15];
    const float* op_g  = (const float*)d_in[16];
    const float* op_be = (const float*)d_in[17];
    const float* op_w2 = (const float*)d_in[18];
    const float* op_b2 = (const float*)d_in[19];
    const float* sigma = (const float*)d_in[20];

    ushort* px16  = (ushort*)d_ws;                              // 3.21 MB
    float* sqnorm = (float*)((char*)d_ws + (size_t)NPIX * 64 * 2);

    k1_range_proj<<<NBLK, 512, 0, stream>>>(
        semantic, rp_w1, rp_b1, rp_g, rp_be, rp_w2, rp_b2, px16, sqnorm);
    k23_fused<<<NBLK, 512, 0, stream>>>(
        px16, sqnorm, semantic, spatial,
        fx_w1, fx_b1, fx_g, fx_be, fx_w2, fx_b2,
        op_w1, op_b1, op_g, op_be, op_w2, op_b2,
        sigma, (float*)d_out);
}

// Round 4
// 189.167 us; speedup vs baseline: 1.0708x; 1.0708x over previous
//
#include <hip/hip_runtime.h>

typedef unsigned short ushort;
typedef unsigned int uint;

constexpr int B = 2, C = 64, H = 112, W = 112;
constexpr int HW = H * W;          // 12544
constexpr int NPIX = B * HW;       // 25088
constexpr int NBLK = 512;          // 2 images x 16x16 tiles of 7x7 -> exactly 2 blocks/CU
constexpr float EPS_LN = 1e-6f, EPS_NORM = 1e-7f;

__device__ __forceinline__ float rcp_fast(float x) { return __builtin_amdgcn_rcpf(x); }
__device__ __forceinline__ float sigmoid_f(float x) { return rcp_fast(1.f + __expf(-x)); }
// Force wave-uniformity so the compiler emits s_load for weight rows.
__device__ __forceinline__ int uni(int x) { return __builtin_amdgcn_readfirstlane(x); }
__device__ __forceinline__ int div7s(int x)  { return (x * 9363) >> 16; }   // exact for 0<=x<64
__device__ __forceinline__ int div13s(int x) { return (x * 5042) >> 16; }   // exact for 0<=x<169

// f32 -> bf16 bits (round-nearest-even) + pair pack/unpack.
__device__ __forceinline__ ushort rne16(float x) {
    uint u = __float_as_uint(x);
    u += 0x7fffu + ((u >> 16) & 1u);
    return (ushort)(u >> 16);
}
__device__ __forceinline__ uint pack2(float a, float b) {
    return (uint)rne16(a) | ((uint)rne16(b) << 16);
}
__device__ __forceinline__ float2 up2(uint u) {
    return make_float2(__uint_as_float(u << 16), __uint_as_float(u & 0xffff0000u));
}

// XCD-patch swizzle (BOTH kernels -> producer/consumer share an XCD L2):
// blk&7 -> (image, quadrant); blk>>3 -> tile in the 8x8-tile quadrant.
// 512 blocks = 8 XCD groups x 64 tiles.
__device__ __forceinline__ void decode_blk(int blk, int& b, int& ty, int& tx) {
    int p8 = blk & 7, i = blk >> 3;          // i in [0,64)
    b = p8 >> 2;
    int quad = p8 & 3;
    int lty = i >> 3, ltx = i & 7;           // 8x8 tiles per quadrant
    ty = (quad >> 1) * 8 + lty;              // [0,16)
    tx = (quad & 1) * 8 + ltx;
}

// ---------------------------------------------------------------------------
// k1: px = range_proj(semantic) -> px16[p][64] (bf16) + sqnorm[p].
// Round-0 structure (256 thr, 4 waves x 16 outputs, entry prefetch, no spill)
// at 7x7 tiles: 512 blocks = exactly 2/CU, balanced, 2 waves/SIMD resident.
// Lanes 49..63 idle in pixel space (23% waste; kernel is latency-bound).
// ---------------------------------------------------------------------------
__global__ __launch_bounds__(256) void k1_range_proj(
    const float* __restrict__ sem,
    const float* __restrict__ w1, const float* __restrict__ b1,
    const float* __restrict__ g,  const float* __restrict__ be,
    const float* __restrict__ w2, const float* __restrict__ b2,
    ushort* __restrict__ px16, float* __restrict__ sqnorm)
{
    __shared__ float f_scr[64 * 64];    // [o][pix] (cols 49..63 unused)
    __shared__ float t_scr[64 * 65];    // [o][pix] pitch 65 (transpose buffer)
    __shared__ float pm[4 * 64], ps[4 * 64], p2s[4 * 64];

    const int tid = threadIdx.x, lane = tid & 63, wv = tid >> 6;
    int b, ty, tx; decode_blk(blockIdx.x, b, ty, tx);
    const int lp  = lane < 49 ? lane : 48;       // clamp for safe addressing
    const int py  = div7s(lp), pxl = lp - py * 7;
    const int h = ty * 7 + py, w = tx * 7 + pxl;
    const int hw = h * W + w;
    const bool act = lane < 49;

    float sv[64];
#pragma unroll
    for (int k = 0; k < 64; ++k) sv[k] = sem[(size_t)(b * 64 + k) * HW + hw];

    const int o0 = uni(wv * 16);
    float macc = 0.f, sacc = 0.f;
    for (int j = 0; j < 16; ++j) {
        const int o = o0 + j;                 // uniform -> s_load weight row
        const float* wr = &w1[o * 64];
        float a0 = 0, a1 = 0, a2 = 0, a3 = 0;
#pragma unroll
        for (int k = 0; k < 64; k += 4) {
            a0 += wr[k] * sv[k];       a1 += wr[k + 1] * sv[k + 1];
            a2 += wr[k + 2] * sv[k + 2]; a3 += wr[k + 3] * sv[k + 3];
        }
        float f = (a0 + a1) + (a2 + a3) + b1[o];
        f_scr[o * 64 + lane] = f;      // bank=lane%32: 2-way, free
        macc += f; sacc += f * f;
    }
    pm[wv * 64 + lane] = macc; ps[wv * 64 + lane] = sacc;
    __syncthreads();
    float m  = (pm[lane] + pm[64 + lane] + pm[128 + lane] + pm[192 + lane]) * (1.f / 64.f);
    float va = (ps[lane] + ps[64 + lane] + ps[128 + lane] + ps[192 + lane]) * (1.f / 64.f) - m * m;
    float rstd = rsqrtf(va + EPS_LN);

    float s[64];
#pragma unroll
    for (int k = 0; k < 64; ++k) {
        float y = g[k] * (f_scr[k * 64 + lane] - m) * rstd + be[k];
        s[k] = y * sigmoid_f(y);
    }
    float sq = 0.f;
    for (int j = 0; j < 16; ++j) {
        const int o = o0 + j;                 // uniform
        const float* wr = &w2[o * 64];
        float a0 = 0, a1 = 0, a2 = 0, a3 = 0;
#pragma unroll
        for (int k = 0; k < 64; k += 4) {
            a0 += wr[k] * s[k];        a1 += wr[k + 1] * s[k + 1];
            a2 += wr[k + 2] * s[k + 2]; a3 += wr[k + 3] * s[k + 3];
        }
        float z = (a0 + a1) + (a2 + a3) + b2[o];
        t_scr[o * 65 + lane] = z;      // bank=(o+lane)%32: conflict-free
        sq += z * z;                   // sqnorm from f32 z
    }
    p2s[wv * 64 + lane] = sq;
    __syncthreads();
    if (wv == 0 && act)
        sqnorm[(size_t)b * HW + hw] = p2s[lane] + p2s[64 + lane] + p2s[128 + lane] + p2s[192 + lane];
    // transpose-out: wave wv stores pixels o0..o0+15 (128-B bf16 rows), ii<49
    for (int j = 0; j < 16; ++j) {
        int ii = o0 + j;
        if (ii < 49) {
            int iy = div7s(ii), ix = ii - iy * 7;
            int hwi = (ty * 7 + iy) * W + tx * 7 + ix;
            px16[((size_t)b * HW + hwi) * 64 + lane] = rne16(t_scr[lane * 65 + ii]);
        }
    }
}

// ---------------------------------------------------------------------------
// k23: bilateral weights + gated fixup + normalize + neighborhood reduction +
// output_proj. Round-0 structure (256 thr, 4 waves, entry sv prefetch) at
// 7x7 tiles: halo 13x13=169, LDS arena 69056 B -> 2 blocks/CU, 512 blocks
// = exactly 2/CU balanced. bf16 halo row r = 128 B = 8 chunks of 16 B;
// chunk q stored at q^(r&7).
// ---------------------------------------------------------------------------
__global__ __launch_bounds__(256, 2) void k23_fused(
    const ushort* __restrict__ px16, const float* __restrict__ sqnorm,
    const float* __restrict__ sem,  const float* __restrict__ spat,
    const float* __restrict__ fw1, const float* __restrict__ fb1,
    const float* __restrict__ fg,  const float* __restrict__ fbe,
    const float* __restrict__ fw2, const float* __restrict__ fb2,
    const float* __restrict__ w1, const float* __restrict__ b1,
    const float* __restrict__ g,  const float* __restrict__ be,
    const float* __restrict__ w2, const float* __restrict__ b2,
    const float* __restrict__ sigma_, float* __restrict__ out)
{
    __shared__ __align__(16) float smem[17264];          // 69056 B arena
    ushort* haloA = (ushort*)smem;                       // px halo bf16: fl 0..5408
    ushort* haloB = (ushort*)(smem + 5408);              // spat halo bf16: fl 5408..10816
    float*  comb  = smem + 10816;                        // 49x64 -> ..13952
    float*  fscr  = smem + 13952;                        // 49x64 -> ..17088
    float*  sqn_l = smem + 17088;                        // 169   -> ..17257
    // Phase-local overlays on dead regions:
    //  P3 (haloA dead after P2):
    float*  pm3 = smem;                                  // 256
    float*  ps3 = smem + 256;                            // 256
    float*  pt  = smem + 512;                            // 256
    //  P6 (haloA + haloB dead after P5):
    float*  av  = smem;                                  // 64x64 f32 (0..4096)
    float*  pm6 = smem + 4096;                           // 256
    float*  ps6 = smem + 4352;                           // 256 (ends 4608 < 5408)
    float*  f2  = smem + 5408;                           // 64x64 f32 over dead haloB

    const int tid = threadIdx.x, lane = tid & 63, wv = tid >> 6;
    int b, ty, tx; decode_blk(blockIdx.x, b, ty, tx);
    const int lp  = lane < 49 ? lane : 48;
    const int py  = div7s(lp), pxl = lp - py * 7;
    const int h = ty * 7 + py, w = tx * 7 + pxl;
    const int hw = h * W + w;
    const int h0 = ty * 7 - 3, w0 = tx * 7 - 3;
    const bool act = lane < 49;

    // ---- svv prefetch (P3 input): overlaps both stagings ----
    float sv[64];
#pragma unroll
    for (int k = 0; k < 64; ++k) sv[k] = sem[(size_t)(b * 64 + k) * HW + hw];

    // ---- P4 (hoisted): stage spat halo -> haloB (bf16), 1 thread/halo-pix ----
    if (tid < 169) {
        const int ry = div13s(tid), rx = tid - ry * 13;
        const int hh = h0 + ry, ww = w0 + rx;
        const bool valid = (unsigned)hh < (unsigned)H && (unsigned)ww < (unsigned)W;
        const int soff = hh * W + ww;
        const int rsw = (tid & 7), rb_ = tid << 6;
#pragma unroll
        for (int cq = 0; cq < 8; ++cq) {
            uint4 v = make_uint4(0u, 0u, 0u, 0u);
            if (valid) {
                const float* sp = &spat[(size_t)(b * 64 + 8 * cq) * HW + soff];
                v.x = pack2(sp[0],      sp[HW]);
                v.y = pack2(sp[2 * HW], sp[3 * HW]);
                v.z = pack2(sp[4 * HW], sp[5 * HW]);
                v.w = pack2(sp[6 * HW], sp[7 * HW]);
            }
            *(uint4*)&haloB[rb_ + ((cq ^ rsw) << 3)] = v;
        }
    }

    // ---- P1: stage px halo -> haloA (bf16): 1352 16-B loads over 256 thr ----
    for (int i = 0; i < 6; ++i) {
        int idx = i * 256 + tid;
        if (idx < 1352) {
            int r = idx >> 3, q = idx & 7;
            int ry = div13s(r), rx = r - ry * 13;
            int hh = h0 + ry, ww = w0 + rx;
            bool valid = (unsigned)hh < (unsigned)H && (unsigned)ww < (unsigned)W;
            uint4 v = make_uint4(0u, 0u, 0u, 0u);
            if (valid) v = *(const uint4*)&px16[((size_t)b * HW + hh * W + ww) * 64 + 8 * q];
            *(uint4*)&haloA[(r << 6) + ((q ^ (r & 7)) << 3)] = v;
        }
    }
    if (tid < 169) {
        int ry = div13s(tid), rx = tid - ry * 13;
        int hh = h0 + ry, ww = w0 + rx;
        bool valid = (unsigned)hh < (unsigned)H && (unsigned)ww < (unsigned)W;
        float v = 0.f;
        if (valid) v = sqnorm[(size_t)b * HW + hh * W + ww];
        sqn_l[tid] = v;
    }
    __syncthreads();

    // ---- P2: bilateral weights, neighbors split across waves ----
    const int rbase = py * 13 + pxl;
    const int rp = rbase + 42;          // +3 rows, +3 cols in halo coords
    float cv[64];
#pragma unroll
    for (int q = 0; q < 8; ++q) {
        uint4 v = *(const uint4*)&haloA[(rp << 6) + ((q ^ (rp & 7)) << 3)];
        float2 p0_ = up2(v.x), p1_ = up2(v.y), p2_ = up2(v.z), p3_ = up2(v.w);
        cv[8 * q + 0] = p0_.x; cv[8 * q + 1] = p0_.y;
        cv[8 * q + 2] = p1_.x; cv[8 * q + 3] = p1_.y;
        cv[8 * q + 4] = p2_.x; cv[8 * q + 5] = p2_.y;
        cv[8 * q + 6] = p3_.x; cv[8 * q + 7] = p3_.y;
    }
    const float sqc = sqn_l[rp];
    const float sg_ = sigma_[0];
    const float inv2s2 = rcp_fast(2.f * sg_ * sg_);
    for (int i = 0; i < 13; ++i) {
        int n = uni(wv + 4 * i);
        if (n < 49) {
            int ryn = div7s(n), rxn = n - ryn * 7;
            int dy = ryn - 3, dx = rxn - 3;
            int rn = rbase + ryn * 13 + rxn;
            float d0 = 0, d1 = 0, d2 = 0, d3 = 0;
#pragma unroll
            for (int q = 0; q < 8; ++q) {
                uint4 v = *(const uint4*)&haloA[(rn << 6) + ((q ^ (rn & 7)) << 3)];
                float2 a = up2(v.x), bb = up2(v.y), c = up2(v.z), d = up2(v.w);
                d0 += a.x  * cv[8 * q + 0]; d1 += a.y  * cv[8 * q + 1];
                d2 += bb.x * cv[8 * q + 2]; d3 += bb.y * cv[8 * q + 3];
                d0 += c.x  * cv[8 * q + 4]; d1 += c.y  * cv[8 * q + 5];
                d2 += d.x  * cv[8 * q + 6]; d3 += d.y  * cv[8 * q + 7];
            }
            float dot = (d0 + d1) + (d2 + d3);
            float dist2 = fmaxf(sqn_l[rn] + sqc - 2.f * dot, 0.f);
            bool validn = (unsigned)(h + dy) < (unsigned)H && (unsigned)(w + dx) < (unsigned)W;
            float d2n = (float)(dy * dy + dx * dx);
            comb[n * 64 + lane] = validn ? __expf(-(dist2 * (1.f / 128.f) + d2n * inv2s2)) : 0.f;
        }
    }
    __syncthreads();   // px-halo reads + comb writes done (haloA dead below)

    // ---- P3: gated fixup (fscr dedicated; sv reused as semantic vector) ----
    float cb[49];
#pragma unroll
    for (int n = 0; n < 49; ++n) cb[n] = comb[n * 64 + lane];
    float macc = 0.f, sacc = 0.f;
    for (int i = 0; i < 13; ++i) {
        const int o = uni(wv + 4 * i);   // uniform -> s_load weight row
        if (o < 49) {
            const float* wr = &fw1[o * 113];
            float a0 = 0, a1 = 0, a2 = 0, a3 = 0;
#pragma unroll
            for (int k = 0; k < 48; k += 4) {
                a0 += wr[k] * cb[k];       a1 += wr[k + 1] * cb[k + 1];
                a2 += wr[k + 2] * cb[k + 2]; a3 += wr[k + 3] * cb[k + 3];
            }
            a0 += wr[48] * cb[48];
            const float* wr2 = wr + 49;
#pragma unroll
            for (int k = 0; k < 64; k += 4) {
                a0 += wr2[k] * sv[k];       a1 += wr2[k + 1] * sv[k + 1];
                a2 += wr2[k + 2] * sv[k + 2]; a3 += wr2[k + 3] * sv[k + 3];
            }
            float f = (a0 + a1) + (a2 + a3) + fb1[o];
            fscr[o * 64 + lane] = f;
            macc += f; sacc += f * f;
        }
    }
    pm3[wv * 64 + lane] = macc; ps3[wv * 64 + lane] = sacc;
    __syncthreads();
    {
        float m  = (pm3[lane] + pm3[64 + lane] + pm3[128 + lane] + pm3[192 + lane]) * (1.f / 49.f);
        float va = (ps3[lane] + ps3[64 + lane] + ps3[128 + lane] + ps3[192 + lane]) * (1.f / 49.f) - m * m;
        float rstd = rsqrtf(va + EPS_LN);
        float s[49];
#pragma unroll
        for (int k = 0; k < 49; ++k) {
            float y = fg[k] * (fscr[k * 64 + lane] - m) * rstd + fbe[k];
            s[k] = y * sigmoid_f(y);
        }
        float tacc = 0.f;
        for (int i = 0; i < 13; ++i) {
            const int o = uni(wv + 4 * i);
            if (o < 49) {
                const float* wr = &fw2[o * 49];
                float a0 = 0, a1 = 0, a2 = 0, a3 = 0;
#pragma unroll
                for (int k = 0; k < 48; k += 4) {
                    a0 += wr[k] * s[k];       a1 += wr[k + 1] * s[k + 1];
                    a2 += wr[k + 2] * s[k + 2]; a3 += wr[k + 3] * s[k + 3];
                }
                a0 += wr[48] * s[48];
                float fo = (a0 + a1) + (a2 + a3) + fb2[o];
                float gate = 1.f + sigmoid_f(fo);
                float cx = comb[o * 64 + lane] * gate;   // own rows: no race
                comb[o * 64 + lane] = cx;
                tacc += cx;
            }
        }
        pt[wv * 64 + lane] = tacc;
    }
    __syncthreads();
    const float inv = rcp_fast(pt[lane] + pt[64 + lane] + pt[128 + lane] + pt[192 + lane] + EPS_NORM);

    // ---- P5: weighted neighborhood reduction (haloB, staged at entry) ----
    const int c0 = uni(wv * 16);
    const int qq0 = c0 >> 3;            // wave's two 8-ch chunks
    float acc[16];
#pragma unroll
    for (int j = 0; j < 16; ++j) acc[j] = 0.f;
    for (int n = 0; n < 49; ++n) {
        int ryn = n / 7, rxn = n - ryn * 7;
        int rn = rbase + ryn * 13 + rxn;
        float cn = comb[n * 64 + lane] * inv;
        const int rb_ = rn << 6, rsw = rn & 7;
#pragma unroll
        for (int q = 0; q < 2; ++q) {
            uint4 v = *(const uint4*)&haloB[rb_ + (((qq0 + q) ^ rsw) << 3)];
            float2 a = up2(v.x), bb = up2(v.y), c = up2(v.z), d = up2(v.w);
            acc[8 * q + 0] += cn * a.x;  acc[8 * q + 1] += cn * a.y;
            acc[8 * q + 2] += cn * bb.x; acc[8 * q + 3] += cn * bb.y;
            acc[8 * q + 4] += cn * c.x;  acc[8 * q + 5] += cn * c.y;
            acc[8 * q + 6] += cn * d.x;  acc[8 * q + 7] += cn * d.y;
        }
    }
    __syncthreads();   // haloA/haloB/comb reads done -> av/f2 overlays safe

    // ---- P6: output_proj (f32 overlays on the two dead halo regions) ----
    for (int j = 0; j < 16; ++j) av[(c0 + j) * 64 + lane] = acc[j];
    __syncthreads();
    float xv[64];
#pragma unroll
    for (int k = 0; k < 64; ++k) xv[k] = av[k * 64 + lane];
    float macc2 = 0.f, sacc2 = 0.f;
    for (int j = 0; j < 16; ++j) {
        const int o = c0 + j;             // uniform
        const float* wr = &w1[o * 64];
        float a0 = 0, a1 = 0, a2 = 0, a3 = 0;
#pragma unroll
        for (int k = 0; k < 64; k += 4) {
            a0 += wr[k] * xv[k];       a1 += wr[k + 1] * xv[k + 1];
            a2 += wr[k + 2] * xv[k + 2]; a3 += wr[k + 3] * xv[k + 3];
        }
        float f = (a0 + a1) + (a2 + a3) + b1[o];
        f2[o * 64 + lane] = f;
        macc2 += f; sacc2 += f * f;
    }
    pm6[wv * 64 + lane] = macc2; ps6[wv * 64 + lane] = sacc2;
    __syncthreads();
    float m  = (pm6[lane] + pm6[64 + lane] + pm6[128 + lane] + pm6[192 + lane]) * (1.f / 64.f);
    float va = (ps6[lane] + ps6[64 + lane] + ps6[128 + lane] + ps6[192 + lane]) * (1.f / 64.f) - m * m;
    float rstd = rsqrtf(va + EPS_LN);
    float yv[64];
#pragma unroll
    for (int k = 0; k < 64; ++k)
        yv[k] = g[k] * (f2[k * 64 + lane] - m) * rstd + be[k];
    for (int j = 0; j < 16; ++j) {
        const int o = c0 + j;             // uniform
        const float* wr = &w2[o * 64];
        float a0 = 0, a1 = 0, a2 = 0, a3 = 0;
#pragma unroll
        for (int k = 0; k < 64; k += 4) {
            a0 += wr[k] * yv[k];       a1 += wr[k + 1] * yv[k + 1];
            a2 += wr[k + 2] * yv[k + 2]; a3 += wr[k + 3] * yv[k + 3];
        }
        float z = (a0 + a1) + (a2 + a3) + b2[o];
        if (act) out[(size_t)(b * 64 + o) * HW + hw] = z;
    }
}

extern "C" void kernel_launch(void* const* d_in, const int* in_sizes, int n_in,
                              void* d_out, int out_size, void* d_ws, size_t ws_size,
                              hipStream_t stream)
{
    const float* spatial  = (const float*)d_in[0];
    const float* semantic = (const float*)d_in[1];
    const float* rp_w1 = (const float*)d_in[2];
    const float* rp_b1 = (const float*)d_in[3];
    const float* rp_g  = (const float*)d_in[4];
    const float* rp_be = (const float*)d_in[5];
    const float* rp_w2 = (const float*)d_in[6];
    const float* rp_b2 = (const float*)d_in[7];
    const float* fx_w1 = (const float*)d_in[8];
    const float* fx_b1 = (const float*)d_in[9];
    const float* fx_g  = (const float*)d_in[10];
    const float* fx_be = (const float*)d_in[11];
    const float* fx_w2 = (const float*)d_in[12];
    const float* fx_b2 = (const float*)d_in[13];
    const float* op_w1 = (const float*)d_in[14];
    const float* op_b1 = (const float*)d_in[15];
    const float* op_g  = (const float*)d_in[16];
    const float* op_be = (const float*)d_in[17];
    const float* op_w2 = (const float*)d_in[18];
    const float* op_b2 = (const float*)d_in[19];
    const float* sigma = (const float*)d_in[20];

    ushort* px16  = (ushort*)d_ws;                              // 3.21 MB
    float* sqnorm = (float*)((char*)d_ws + (size_t)NPIX * 64 * 2);

    k1_range_proj<<<NBLK, 256, 0, stream>>>(
        semantic, rp_w1, rp_b1, rp_g, rp_be, rp_w2, rp_b2, px16, sqnorm);
    k23_fused<<<NBLK, 256, 0, stream>>>(
        px16, sqnorm, semantic, spatial,
        fx_w1, fx_b1, fx_g, fx_be, fx_w2, fx_b2,
        op_w1, op_b1, op_g, op_be, op_w2, op_b2,
        sigma, (float*)d_out);
}

// Round 5
// 185.485 us; speedup vs baseline: 1.0920x; 1.0198x over previous
//
#include <hip/hip_runtime.h>

typedef unsigned short ushort;
typedef unsigned int uint;

constexpr int B = 2, C = 64, H = 112, W = 112;
constexpr int HW = H * W;          // 12544
constexpr int NPIX = B * HW;       // 25088
constexpr int NBLK = 512;          // 2 images x 16x16 tiles of 7x7 -> exactly 2 blocks/CU
constexpr float EPS_LN = 1e-6f, EPS_NORM = 1e-7f;

__device__ __forceinline__ float rcp_fast(float x) { return __builtin_amdgcn_rcpf(x); }
__device__ __forceinline__ float sigmoid_f(float x) { return rcp_fast(1.f + __expf(-x)); }
// Force wave-uniformity so the compiler emits scalar/uniform addressing.
__device__ __forceinline__ int uni(int x) { return __builtin_amdgcn_readfirstlane(x); }
__device__ __forceinline__ int div7s(int x)  { return (x * 9363) >> 16; }   // exact for 0<=x<64
__device__ __forceinline__ int div13s(int x) { return (x * 5042) >> 16; }   // exact for 0<=x<169
__device__ __forceinline__ int div49s(int x) { return (x * 1338) >> 16; }   // exact for 0<=x<2520

// f32 -> bf16 bits (round-nearest-even) + pair pack/unpack.
__device__ __forceinline__ ushort rne16(float x) {
    uint u = __float_as_uint(x);
    u += 0x7fffu + ((u >> 16) & 1u);
    return (ushort)(u >> 16);
}
__device__ __forceinline__ uint pack2(float a, float b) {
    return (uint)rne16(a) | ((uint)rne16(b) << 16);
}
__device__ __forceinline__ float2 up2(uint u) {
    return make_float2(__uint_as_float(u << 16), __uint_as_float(u & 0xffff0000u));
}

// XCD-patch swizzle (BOTH kernels -> producer/consumer share an XCD L2).
__device__ __forceinline__ void decode_blk(int blk, int& b, int& ty, int& tx) {
    int p8 = blk & 7, i = blk >> 3;          // i in [0,64)
    b = p8 >> 2;
    int quad = p8 & 3;
    int lty = i >> 3, ltx = i & 7;           // 8x8 tiles per quadrant
    ty = (quad >> 1) * 8 + lty;              // [0,16)
    tx = (quad & 1) * 8 + ltx;
}

// ---------------------------------------------------------------------------
// k1: px = range_proj(semantic) -> px16[p][64] (bf16) + sqnorm[p].
// NEW (r5): w1+w2 staged into LDS at entry. The conv j-loops previously
// fetched each weight row via s_load (SGPR file fits ONE row -> no
// double-buffer -> ~200-cyc lgkm stall per j). LDS broadcast reads are
// conflict-free and pipeline under the FMAs. Same f32 math, bit-identical.
// ---------------------------------------------------------------------------
__global__ __launch_bounds__(256) void k1_range_proj(
    const float* __restrict__ sem,
    const float* __restrict__ w1, const float* __restrict__ b1,
    const float* __restrict__ g,  const float* __restrict__ be,
    const float* __restrict__ w2, const float* __restrict__ b2,
    ushort* __restrict__ px16, float* __restrict__ sqnorm)
{
    __shared__ float f_scr[64 * 64];    // [o][pix] (cols 49..63 unused)
    __shared__ float t_scr[64 * 65];    // [o][pix] pitch 65 (transpose buffer)
    __shared__ float pm[4 * 64], ps[4 * 64], p2s[4 * 64];
    __shared__ __align__(16) float wlds[8192];   // w1 @0, w2 @4096

    const int tid = threadIdx.x, lane = tid & 63, wv = tid >> 6;
    int b, ty, tx; decode_blk(blockIdx.x, b, ty, tx);
    const int lp  = lane < 49 ? lane : 48;       // clamp for safe addressing
    const int py  = div7s(lp), pxl = lp - py * 7;
    const int h = ty * 7 + py, w = tx * 7 + pxl;
    const int hw = h * W + w;
    const bool act = lane < 49;

    float sv[64];
#pragma unroll
    for (int k = 0; k < 64; ++k) sv[k] = sem[(size_t)(b * 64 + k) * HW + hw];

    // stage both weight matrices (coalesced float4, 8/thread)
    {
        float4* d4 = (float4*)wlds;
        const float4* s1 = (const float4*)w1;
        const float4* s2 = (const float4*)w2;
#pragma unroll
        for (int i = 0; i < 4; ++i) d4[i * 256 + tid] = s1[i * 256 + tid];
#pragma unroll
        for (int i = 0; i < 4; ++i) d4[1024 + i * 256 + tid] = s2[i * 256 + tid];
    }
    __syncthreads();

    const int o0 = uni(wv * 16);
    float macc = 0.f, sacc = 0.f;
    for (int j = 0; j < 16; ++j) {
        const int o = o0 + j;                 // uniform -> broadcast ds_read
        const float* wr = &wlds[o * 64];
        float a0 = 0, a1 = 0, a2 = 0, a3 = 0;
#pragma unroll
        for (int k = 0; k < 64; k += 4) {
            a0 += wr[k] * sv[k];       a1 += wr[k + 1] * sv[k + 1];
            a2 += wr[k + 2] * sv[k + 2]; a3 += wr[k + 3] * sv[k + 3];
        }
        float f = (a0 + a1) + (a2 + a3) + b1[o];
        f_scr[o * 64 + lane] = f;      // bank=lane%32: 2-way, free
        macc += f; sacc += f * f;
    }
    pm[wv * 64 + lane] = macc; ps[wv * 64 + lane] = sacc;
    __syncthreads();
    float m  = (pm[lane] + pm[64 + lane] + pm[128 + lane] + pm[192 + lane]) * (1.f / 64.f);
    float va = (ps[lane] + ps[64 + lane] + ps[128 + lane] + ps[192 + lane]) * (1.f / 64.f) - m * m;
    float rstd = rsqrtf(va + EPS_LN);

    float s[64];
#pragma unroll
    for (int k = 0; k < 64; ++k) {
        float y = g[k] * (f_scr[k * 64 + lane] - m) * rstd + be[k];
        s[k] = y * sigmoid_f(y);
    }
    float sq = 0.f;
    for (int j = 0; j < 16; ++j) {
        const int o = o0 + j;                 // uniform
        const float* wr = &wlds[4096 + o * 64];
        float a0 = 0, a1 = 0, a2 = 0, a3 = 0;
#pragma unroll
        for (int k = 0; k < 64; k += 4) {
            a0 += wr[k] * s[k];        a1 += wr[k + 1] * s[k + 1];
            a2 += wr[k + 2] * s[k + 2]; a3 += wr[k + 3] * s[k + 3];
        }
        float z = (a0 + a1) + (a2 + a3) + b2[o];
        t_scr[o * 65 + lane] = z;      // bank=(o+lane)%32: conflict-free
        sq += z * z;                   // sqnorm from f32 z
    }
    p2s[wv * 64 + lane] = sq;
    __syncthreads();
    if (wv == 0 && act)
        sqnorm[(size_t)b * HW + hw] = p2s[lane] + p2s[64 + lane] + p2s[128 + lane] + p2s[192 + lane];
    // transpose-out: wave wv stores pixels o0..o0+15 (128-B bf16 rows), ii<49
    for (int j = 0; j < 16; ++j) {
        int ii = o0 + j;
        if (ii < 49) {
            int iy = div7s(ii), ix = ii - iy * 7;
            int hwi = (ty * 7 + iy) * W + tx * 7 + ix;
            px16[((size_t)b * HW + hwi) * 64 + lane] = rne16(t_scr[lane * 65 + ii]);
        }
    }
}

// ---------------------------------------------------------------------------
// k23: bilateral weights + gated fixup + normalize + neighborhood reduction +
// output_proj. 256 thr / 7x7 tile, 512 blocks = 2/CU. NEW (r5): weight
// matrices staged into LDS via time-multiplexed overlays on dead regions:
//   P3: fx_w1 comb-half (49x49) + fx_w2 (49x49) -> dead haloA (post-P2)
//   P5: op_w1 (64x64)  -> same region (dead after P3), staged UNDER P5 compute
//   P6a: op_w2 (64x64) -> dead fscr/sqn/partials strip, staged under conv-a
// Arena 72192 B -> still 2 blocks/CU. Same f32 math as r4 (bit-identical).
// ---------------------------------------------------------------------------
__global__ __launch_bounds__(256, 2) void k23_fused(
    const ushort* __restrict__ px16, const float* __restrict__ sqnorm,
    const float* __restrict__ sem,  const float* __restrict__ spat,
    const float* __restrict__ fw1, const float* __restrict__ fb1,
    const float* __restrict__ fg,  const float* __restrict__ fbe,
    const float* __restrict__ fw2, const float* __restrict__ fb2,
    const float* __restrict__ w1, const float* __restrict__ b1,
    const float* __restrict__ g,  const float* __restrict__ be,
    const float* __restrict__ w2, const float* __restrict__ b2,
    const float* __restrict__ sigma_, float* __restrict__ out)
{
    __shared__ __align__(16) float smem[18048];          // 72192 B arena
    ushort* haloA = (ushort*)smem;                       // px halo bf16: fl 0..5408
    ushort* haloB = (ushort*)(smem + 5408);              // spat halo bf16: fl 5408..10816
    float*  comb  = smem + 10816;                        // 49x64 -> ..13952
    float*  fscr  = smem + 13952;                        // 49x64 -> ..17088
    float*  sqn_l = smem + 17088;                        // 169   -> ..17257 (dead after P2)
    float*  pm3   = smem + 17264;                        // 256 (P3 LN partials)
    float*  ps3   = smem + 17520;                        // 256
    float*  pt    = smem + 17776;                        // 256 -> ..18032 (dead before P6)
    // Phase-local overlays:
    float*  fwc  = smem;                                 // P3: fx_w1[:, :49] (2401) over dead haloA
    float*  fw2l = smem + 2401;                          // P3: fx_w2 (2401)  -> ..4802 <= 5408
    float*  w1l  = smem;                                 // P6a: op_w1 (4096), staged during P5
    float*  pm6  = smem + 4096;                          // P6 partials (256) ..4352
    float*  ps6  = smem + 4352;                          // P6 partials (256) ..4608 <= 5408
    float*  av   = smem + 5408;                          // P6: 64x64 over dead haloB
    float*  f2   = smem + 5408;                          // P6b: over dead av (barrier-separated)
    float*  w2l  = smem + 13952;                         // P6b: op_w2 (4096) over dead fscr/sqn/pm3/ps3/pt

    const int tid = threadIdx.x, lane = tid & 63, wv = tid >> 6;
    int b, ty, tx; decode_blk(blockIdx.x, b, ty, tx);
    const int lp  = lane < 49 ? lane : 48;
    const int py  = div7s(lp), pxl = lp - py * 7;
    const int h = ty * 7 + py, w = tx * 7 + pxl;
    const int hw = h * W + w;
    const int h0 = ty * 7 - 3, w0 = tx * 7 - 3;
    const bool act = lane < 49;

    // ---- svv prefetch (P3 input): overlaps both stagings ----
    float sv[64];
#pragma unroll
    for (int k = 0; k < 64; ++k) sv[k] = sem[(size_t)(b * 64 + k) * HW + hw];

    // ---- P4 (hoisted): stage spat halo -> haloB (bf16), 1 thread/halo-pix ----
    if (tid < 169) {
        const int ry = div13s(tid), rx = tid - ry * 13;
        const int hh = h0 + ry, ww = w0 + rx;
        const bool valid = (unsigned)hh < (unsigned)H && (unsigned)ww < (unsigned)W;
        const int soff = hh * W + ww;
        const int rsw = (tid & 7), rb_ = tid << 6;
#pragma unroll
        for (int cq = 0; cq < 8; ++cq) {
            uint4 v = make_uint4(0u, 0u, 0u, 0u);
            if (valid) {
                const float* sp = &spat[(size_t)(b * 64 + 8 * cq) * HW + soff];
                v.x = pack2(sp[0],      sp[HW]);
                v.y = pack2(sp[2 * HW], sp[3 * HW]);
                v.z = pack2(sp[4 * HW], sp[5 * HW]);
                v.w = pack2(sp[6 * HW], sp[7 * HW]);
            }
            *(uint4*)&haloB[rb_ + ((cq ^ rsw) << 3)] = v;
        }
    }

    // ---- P1: stage px halo -> haloA (bf16): 1352 16-B loads over 256 thr ----
    for (int i = 0; i < 6; ++i) {
        int idx = i * 256 + tid;
        if (idx < 1352) {
            int r = idx >> 3, q = idx & 7;
            int ry = div13s(r), rx = r - ry * 13;
            int hh = h0 + ry, ww = w0 + rx;
            bool valid = (unsigned)hh < (unsigned)H && (unsigned)ww < (unsigned)W;
            uint4 v = make_uint4(0u, 0u, 0u, 0u);
            if (valid) v = *(const uint4*)&px16[((size_t)b * HW + hh * W + ww) * 64 + 8 * q];
            *(uint4*)&haloA[(r << 6) + ((q ^ (r & 7)) << 3)] = v;
        }
    }
    if (tid < 169) {
        int ry = div13s(tid), rx = tid - ry * 13;
        int hh = h0 + ry, ww = w0 + rx;
        bool valid = (unsigned)hh < (unsigned)H && (unsigned)ww < (unsigned)W;
        float v = 0.f;
        if (valid) v = sqnorm[(size_t)b * HW + hh * W + ww];
        sqn_l[tid] = v;
    }
    __syncthreads();

    // ---- P2: bilateral weights, neighbors split across waves ----
    const int rbase = py * 13 + pxl;
    const int rp = rbase + 42;          // +3 rows, +3 cols in halo coords
    {
        float cv[64];
#pragma unroll
        for (int q = 0; q < 8; ++q) {
            uint4 v = *(const uint4*)&haloA[(rp << 6) + ((q ^ (rp & 7)) << 3)];
            float2 p0_ = up2(v.x), p1_ = up2(v.y), p2_ = up2(v.z), p3_ = up2(v.w);
            cv[8 * q + 0] = p0_.x; cv[8 * q + 1] = p0_.y;
            cv[8 * q + 2] = p1_.x; cv[8 * q + 3] = p1_.y;
            cv[8 * q + 4] = p2_.x; cv[8 * q + 5] = p2_.y;
            cv[8 * q + 6] = p3_.x; cv[8 * q + 7] = p3_.y;
        }
        const float sqc = sqn_l[rp];
        const float sg_ = sigma_[0];
        const float inv2s2 = rcp_fast(2.f * sg_ * sg_);
        for (int i = 0; i < 13; ++i) {
            int n = uni(wv + 4 * i);
            if (n < 49) {
                int ryn = div7s(n), rxn = n - ryn * 7;
                int dy = ryn - 3, dx = rxn - 3;
                int rn = rbase + ryn * 13 + rxn;
                float d0 = 0, d1 = 0, d2 = 0, d3 = 0;
#pragma unroll
                for (int q = 0; q < 8; ++q) {
                    uint4 v = *(const uint4*)&haloA[(rn << 6) + ((q ^ (rn & 7)) << 3)];
                    float2 a = up2(v.x), bb = up2(v.y), c = up2(v.z), d = up2(v.w);
                    d0 += a.x  * cv[8 * q + 0]; d1 += a.y  * cv[8 * q + 1];
                    d2 += bb.x * cv[8 * q + 2]; d3 += bb.y * cv[8 * q + 3];
                    d0 += c.x  * cv[8 * q + 4]; d1 += c.y  * cv[8 * q + 5];
                    d2 += d.x  * cv[8 * q + 6]; d3 += d.y  * cv[8 * q + 7];
                }
                float dot = (d0 + d1) + (d2 + d3);
                float dist2 = fmaxf(sqn_l[rn] + sqc - 2.f * dot, 0.f);
                bool validn = (unsigned)(h + dy) < (unsigned)H && (unsigned)(w + dx) < (unsigned)W;
                float d2n = (float)(dy * dy + dx * dx);
                comb[n * 64 + lane] = validn ? __expf(-(dist2 * (1.f / 128.f) + d2n * inv2s2)) : 0.f;
            }
        }
    }
    __syncthreads();   // px-halo reads + comb writes done (haloA dead below)

    // ---- stage fixup weights into dead haloA region ----
    for (int i = tid; i < 2401; i += 256) {
        int o = div49s(i);                     // i/49
        fwc[i]  = fw1[o * 113 + (i - o * 49)]; // comb-half of fx_w1
        fw2l[i] = fw2[i];                      // fx_w2 (contiguous)
    }
    __syncthreads();

    // ---- P3: gated fixup (fscr dedicated; sv reused as semantic vector) ----
    float cb[49];
#pragma unroll
    for (int n = 0; n < 49; ++n) cb[n] = comb[n * 64 + lane];
    float macc = 0.f, sacc = 0.f;
    for (int i = 0; i < 13; ++i) {
        const int o = uni(wv + 4 * i);   // uniform -> broadcast ds_read (comb part)
        if (o < 49) {
            const float* wr = &fwc[o * 49];
            float a0 = 0, a1 = 0, a2 = 0, a3 = 0;
#pragma unroll
            for (int k = 0; k < 48; k += 4) {
                a0 += wr[k] * cb[k];       a1 += wr[k + 1] * cb[k + 1];
                a2 += wr[k + 2] * cb[k + 2]; a3 += wr[k + 3] * cb[k + 3];
            }
            a0 += wr[48] * cb[48];
            const float* wr2 = &fw1[o * 113 + 49];   // sem-half stays s_load
#pragma unroll
            for (int k = 0; k < 64; k += 4) {
                a0 += wr2[k] * sv[k];       a1 += wr2[k + 1] * sv[k + 1];
                a2 += wr2[k + 2] * sv[k + 2]; a3 += wr2[k + 3] * sv[k + 3];
            }
            float f = (a0 + a1) + (a2 + a3) + fb1[o];
            fscr[o * 64 + lane] = f;
            macc += f; sacc += f * f;
        }
    }
    pm3[wv * 64 + lane] = macc; ps3[wv * 64 + lane] = sacc;
    __syncthreads();
    {
        float m  = (pm3[lane] + pm3[64 + lane] + pm3[128 + lane] + pm3[192 + lane]) * (1.f / 49.f);
        float va = (ps3[lane] + ps3[64 + lane] + ps3[128 + lane] + ps3[192 + lane]) * (1.f / 49.f) - m * m;
        float rstd = rsqrtf(va + EPS_LN);
        float s[49];
#pragma unroll
        for (int k = 0; k < 49; ++k) {
            float y = fg[k] * (fscr[k * 64 + lane] - m) * rstd + fbe[k];
            s[k] = y * sigmoid_f(y);
        }
        float tacc = 0.f;
        for (int i = 0; i < 13; ++i) {
            const int o = uni(wv + 4 * i);
            if (o < 49) {
                const float* wr = &fw2l[o * 49];     // LDS broadcast
                float a0 = 0, a1 = 0, a2 = 0, a3 = 0;
#pragma unroll
                for (int k = 0; k < 48; k += 4) {
                    a0 += wr[k] * s[k];       a1 += wr[k + 1] * s[k + 1];
                    a2 += wr[k + 2] * s[k + 2]; a3 += wr[k + 3] * s[k + 3];
                }
                a0 += wr[48] * s[48];
                float fo = (a0 + a1) + (a2 + a3) + fb2[o];
                float gate = 1.f + sigmoid_f(fo);
                float cx = comb[o * 64 + lane] * gate;   // own rows: no race
                comb[o * 64 + lane] = cx;
                tacc += cx;
            }
        }
        pt[wv * 64 + lane] = tacc;
    }
    __syncthreads();
    const float inv = rcp_fast(pt[lane] + pt[64 + lane] + pt[128 + lane] + pt[192 + lane] + EPS_NORM);

    // ---- stage op_w1 into dead haloA/fw region; hides under P5 compute ----
    {
        const float4* s4 = (const float4*)w1;
        float4* d4 = (float4*)smem;
#pragma unroll
        for (int i = 0; i < 4; ++i) d4[i * 256 + tid] = s4[i * 256 + tid];
    }

    // ---- P5: weighted neighborhood reduction (haloB, staged at entry) ----
    const int c0 = uni(wv * 16);
    const int qq0 = c0 >> 3;            // wave's two 8-ch chunks
    float acc[16];
#pragma unroll
    for (int j = 0; j < 16; ++j) acc[j] = 0.f;
    for (int n = 0; n < 49; ++n) {
        int ryn = n / 7, rxn = n - ryn * 7;
        int rn = rbase + ryn * 13 + rxn;
        float cn = comb[n * 64 + lane] * inv;
        const int rb_ = rn << 6, rsw = rn & 7;
#pragma unroll
        for (int q = 0; q < 2; ++q) {
            uint4 v = *(const uint4*)&haloB[rb_ + (((qq0 + q) ^ rsw) << 3)];
            float2 a = up2(v.x), bb = up2(v.y), c = up2(v.z), d = up2(v.w);
            acc[8 * q + 0] += cn * a.x;  acc[8 * q + 1] += cn * a.y;
            acc[8 * q + 2] += cn * bb.x; acc[8 * q + 3] += cn * bb.y;
            acc[8 * q + 4] += cn * c.x;  acc[8 * q + 5] += cn * c.y;
            acc[8 * q + 6] += cn * d.x;  acc[8 * q + 7] += cn * d.y;
        }
    }
    __syncthreads();   // haloB/comb reads + w1l staging done -> av overlay safe

    // ---- P6: output_proj (overlays on dead regions) ----
    for (int j = 0; j < 16; ++j) av[(c0 + j) * 64 + lane] = acc[j];
    __syncthreads();
    float xv[64];
#pragma unroll
    for (int k = 0; k < 64; ++k) xv[k] = av[k * 64 + lane];
    __syncthreads();   // av fully read -> f2 may overwrite it
    // stage op_w2 into dead fscr/sqn/partials strip (hides under conv-a)
    {
        const float4* s4 = (const float4*)w2;
        float4* d4 = (float4*)(smem + 13952);
#pragma unroll
        for (int i = 0; i < 4; ++i) d4[i * 256 + tid] = s4[i * 256 + tid];
    }
    float macc2 = 0.f, sacc2 = 0.f;
    for (int j = 0; j < 16; ++j) {
        const int o = c0 + j;             // uniform -> LDS broadcast
        const float* wr = &w1l[o * 64];
        float a0 = 0, a1 = 0, a2 = 0, a3 = 0;
#pragma unroll
        for (int k = 0; k < 64; k += 4) {
            a0 += wr[k] * xv[k];       a1 += wr[k + 1] * xv[k + 1];
            a2 += wr[k + 2] * xv[k + 2]; a3 += wr[k + 3] * xv[k + 3];
        }
        float f = (a0 + a1) + (a2 + a3) + b1[o];
        f2[o * 64 + lane] = f;
        macc2 += f; sacc2 += f * f;
    }
    pm6[wv * 64 + lane] = macc2; ps6[wv * 64 + lane] = sacc2;
    __syncthreads();
    float m  = (pm6[lane] + pm6[64 + lane] + pm6[128 + lane] + pm6[192 + lane]) * (1.f / 64.f);
    float va = (ps6[lane] + ps6[64 + lane] + ps6[128 + lane] + ps6[192 + lane]) * (1.f / 64.f) - m * m;
    float rstd = rsqrtf(va + EPS_LN);
    float yv[64];
#pragma unroll
    for (int k = 0; k < 64; ++k)
        yv[k] = g[k] * (f2[k * 64 + lane] - m) * rstd + be[k];
    for (int j = 0; j < 16; ++j) {
        const int o = c0 + j;             // uniform -> LDS broadcast
        const float* wr = &w2l[o * 64];
        float a0 = 0, a1 = 0, a2 = 0, a3 = 0;
#pragma unroll
        for (int k = 0; k < 64; k += 4) {
            a0 += wr[k] * yv[k];       a1 += wr[k + 1] * yv[k + 1];
            a2 += wr[k + 2] * yv[k + 2]; a3 += wr[k + 3] * yv[k + 3];
        }
        float z = (a0 + a1) + (a2 + a3) + b2[o];
        if (act) out[(size_t)(b * 64 + o) * HW + hw] = z;
    }
}

extern "C" void kernel_launch(void* const* d_in, const int* in_sizes, int n_in,
                              void* d_out, int out_size, void* d_ws, size_t ws_size,
                              hipStream_t stream)
{
    const float* spatial  = (const float*)d_in[0];
    const float* semantic = (const float*)d_in[1];
    const float* rp_w1 = (const float*)d_in[2];
    const float* rp_b1 = (const float*)d_in[3];
    const float* rp_g  = (const float*)d_in[4];
    const float* rp_be = (const float*)d_in[5];
    const float* rp_w2 = (const float*)d_in[6];
    const float* rp_b2 = (const float*)d_in[7];
    const float* fx_w1 = (const float*)d_in[8];
    const float* fx_b1 = (const float*)d_in[9];
    const float* fx_g  = (const float*)d_in[10];
    const float* fx_be = (const float*)d_in[11];
    const float* fx_w2 = (const float*)d_in[12];
    const float* fx_b2 = (const float*)d_in[13];
    const float* op_w1 = (const float*)d_in[14];
    const float* op_b1 = (const float*)d_in[15];
    const float* op_g  = (const float*)d_in[16];
    const float* op_be = (const float*)d_in[17];
    const float* op_w2 = (const float*)d_in[18];
    const float* op_b2 = (const float*)d_in[19];
    const float* sigma = (const float*)d_in[20];

    ushort* px16  = (ushort*)d_ws;                              // 3.21 MB
    float* sqnorm = (float*)((char*)d_ws + (size_t)NPIX * 64 * 2);

    k1_range_proj<<<NBLK, 256, 0, stream>>>(
        semantic, rp_w1, rp_b1, rp_g, rp_be, rp_w2, rp_b2, px16, sqnorm);
    k23_fused<<<NBLK, 256, 0, stream>>>(
        px16, sqnorm, semantic, spatial,
        fx_w1, fx_b1, fx_g, fx_be, fx_w2, fx_b2,
        op_w1, op_b1, op_g, op_be, op_w2, op_b2,
        sigma, (float*)d_out);
}

// Round 6
// 158.991 us; speedup vs baseline: 1.2740x; 1.1666x over previous
//
#include <hip/hip_runtime.h>

typedef unsigned short ushort;
typedef unsigned int uint;

constexpr int B = 2, C = 64, H = 112, W = 112;
constexpr int HW = H * W;          // 12544
constexpr int NPIX = B * HW;       // 25088
constexpr int NBLK = 512;          // 2 images x 16x16 tiles of 7x7 -> exactly 2 blocks/CU
constexpr float EPS_LN = 1e-6f, EPS_NORM = 1e-7f;

typedef __attribute__((ext_vector_type(8))) short bf16x8;   // 8 bf16 = 4 VGPRs
typedef __attribute__((ext_vector_type(4))) float f32x4;

__device__ __forceinline__ float rcp_fast(float x) { return __builtin_amdgcn_rcpf(x); }
__device__ __forceinline__ float sigmoid_f(float x) { return rcp_fast(1.f + __expf(-x)); }
__device__ __forceinline__ int uni(int x) { return __builtin_amdgcn_readfirstlane(x); }
__device__ __forceinline__ int div7s(int x)  { return (x * 9363) >> 16; }   // exact for 0<=x<64
__device__ __forceinline__ int div13s(int x) { return (x * 5042) >> 16; }   // exact for 0<=x<169
__device__ __forceinline__ int div49s(int x) { return (x * 1338) >> 16; }   // exact for 0<=x<2520

// f32 -> bf16 bits (round-nearest-even) + pair pack/unpack.
__device__ __forceinline__ ushort rne16(float x) {
    uint u = __float_as_uint(x);
    u += 0x7fffu + ((u >> 16) & 1u);
    return (ushort)(u >> 16);
}
__device__ __forceinline__ uint pack2(float a, float b) {
    return (uint)rne16(a) | ((uint)rne16(b) << 16);
}
__device__ __forceinline__ float2 up2(uint u) {
    return make_float2(__uint_as_float(u << 16), __uint_as_float(u & 0xffff0000u));
}

__device__ __forceinline__ f32x4 mfma16(bf16x8 a, bf16x8 b, f32x4 c) {
    return __builtin_amdgcn_mfma_f32_16x16x32_bf16(a, b, c, 0, 0, 0);
}

// XCD-patch swizzle (BOTH kernels -> producer/consumer share an XCD L2).
__device__ __forceinline__ void decode_blk(int blk, int& b, int& ty, int& tx) {
    int p8 = blk & 7, i = blk >> 3;          // i in [0,64)
    b = p8 >> 2;
    int quad = p8 & 3;
    int lty = i >> 3, ltx = i & 7;           // 8x8 tiles per quadrant
    ty = (quad >> 1) * 8 + lty;              // [0,16)
    tx = (quad & 1) * 8 + ltx;
}

// ---------------------------------------------------------------------------
// Split-bf16 GEMM helpers. Layout: activations/weights as [64 rows][72] bf16
// (pitch 72 -> 144B rows: 16B-aligned b128 frags, 2-way banks = free).
// mfma_f32_16x16x32_bf16 fragments: A row=lane&15, k=(lane>>4)*8+j;
// B col=lane&15, k=(lane>>4)*8+j; D col=lane&15, row=(lane>>4)*4+reg.
// 3-term split (ah*bh + ah*bl + al*bh): error ~2^-16 rel ~= f32 accuracy.
// ---------------------------------------------------------------------------
__device__ __forceinline__ void stage_w(const float* __restrict__ wsrc,
                                        ushort* wh, ushort* wl, int tid)
{
#pragma unroll
    for (int i = 0; i < 8; ++i) {
        int idx2 = i * 256 + tid;            // 2048 float pairs = 64x64
        int o = idx2 >> 5, k = (idx2 & 31) * 2;
        float2 xy = *(const float2*)&wsrc[o * 64 + k];
        uint h = pack2(xy.x, xy.y);
        *(uint*)&wh[o * 72 + k] = h;
        *(uint*)&wl[o * 72 + k] = pack2(xy.x - __uint_as_float((h & 0xffffu) << 16),
                                        xy.y - __uint_as_float(h & 0xffff0000u));
    }
}

// D(64x64) = W(64x64) . X(64x64) + bias, this lane covers col pp, rows
// (mt*16 + l4*4 + r). acc[4] of f32x4.
__device__ __forceinline__ void gemm64(const ushort* __restrict__ wh, const ushort* __restrict__ wl,
                                       const ushort* __restrict__ xh, const ushort* __restrict__ xl,
                                       const float* __restrict__ bias,
                                       int lm, int l4, int pp, f32x4 acc[4])
{
#pragma unroll
    for (int mt = 0; mt < 4; ++mt) {
        const int ob = mt * 16 + l4 * 4;
        acc[mt][0] = bias[ob]; acc[mt][1] = bias[ob + 1];
        acc[mt][2] = bias[ob + 2]; acc[mt][3] = bias[ob + 3];
    }
#pragma unroll
    for (int kt = 0; kt < 2; ++kt) {
        const int xo = pp * 72 + kt * 32 + l4 * 8;
        bf16x8 bh = *(const bf16x8*)&xh[xo];
        bf16x8 bl = *(const bf16x8*)&xl[xo];
#pragma unroll
        for (int mt = 0; mt < 4; ++mt) {
            const int wo = (mt * 16 + lm) * 72 + kt * 32 + l4 * 8;
            bf16x8 ah = *(const bf16x8*)&wh[wo];
            bf16x8 al = *(const bf16x8*)&wl[wo];
            acc[mt] = mfma16(al, bh, acc[mt]);
            acc[mt] = mfma16(ah, bl, acc[mt]);
            acc[mt] = mfma16(ah, bh, acc[mt]);
        }
    }
}

// ---------------------------------------------------------------------------
// k1: px = range_proj(semantic) -> px16[p][64] (bf16) + sqnorm[p].
// FULL MFMA rewrite (r6): both 64x64 convs as split-bf16 MFMA GEMMs.
// LN/sqnorm via 4-lane __shfl_xor (lanes {lm,+16,+32,+48} share a pixel).
// LDS 56.3KB -> 2 blocks/CU.
// ---------------------------------------------------------------------------
__global__ __launch_bounds__(256) void k1_range_proj(
    const float* __restrict__ sem,
    const float* __restrict__ w1, const float* __restrict__ b1,
    const float* __restrict__ g,  const float* __restrict__ be,
    const float* __restrict__ w2, const float* __restrict__ b2,
    ushort* __restrict__ px16, float* __restrict__ sqnorm)
{
    __shared__ __align__(16) ushort u16[28160];   // 56320 B
    ushort* wh1 = u16;                 // [64][72] each (4608 ushorts)
    ushort* wl1 = u16 + 4608;
    ushort* wh2 = u16 + 9216;
    ushort* wl2 = u16 + 13824;
    ushort* xh  = u16 + 18432;         // activations / s (reused)
    ushort* xl  = u16 + 23040;         // ..27648
    float*  bv  = (float*)(u16 + 27648);   // b1|g|be|b2 (256 floats)

    const int tid = threadIdx.x, lane = tid & 63, wv = tid >> 6;
    const int lm = lane & 15, l4 = lane >> 4;
    int b, ty, tx; decode_blk(blockIdx.x, b, ty, tx);

    // ---- stage activations: wave wv loads channels [wv*16,+16) of pixel=lane
    {
        const int lp = lane < 49 ? lane : 48;
        const int py = div7s(lp), px = lp - py * 7;
        const int hw = (ty * 7 + py) * W + tx * 7 + px;
        const bool a = lane < 49;
        float xv[16];
#pragma unroll
        for (int j = 0; j < 16; ++j)
            xv[j] = a ? sem[(size_t)(b * 64 + wv * 16 + j) * HW + hw] : 0.f;
        uint hu[8], lu[8];
#pragma unroll
        for (int jj = 0; jj < 8; ++jj) {
            uint hh = pack2(xv[2 * jj], xv[2 * jj + 1]);
            hu[jj] = hh;
            lu[jj] = pack2(xv[2 * jj]     - __uint_as_float((hh & 0xffffu) << 16),
                           xv[2 * jj + 1] - __uint_as_float(hh & 0xffff0000u));
        }
        const int rb = lane * 72 + wv * 16;
        *(uint4*)&xh[rb]     = make_uint4(hu[0], hu[1], hu[2], hu[3]);
        *(uint4*)&xh[rb + 8] = make_uint4(hu[4], hu[5], hu[6], hu[7]);
        *(uint4*)&xl[rb]     = make_uint4(lu[0], lu[1], lu[2], lu[3]);
        *(uint4*)&xl[rb + 8] = make_uint4(lu[4], lu[5], lu[6], lu[7]);
    }
    stage_w(w1, wh1, wl1, tid);
    stage_w(w2, wh2, wl2, tid);
    if (tid < 64) { bv[tid] = b1[tid]; bv[64 + tid] = g[tid];
                    bv[128 + tid] = be[tid]; bv[192 + tid] = b2[tid]; }
    __syncthreads();

    const int pp = wv * 16 + lm;       // this lane's pixel for MFMA phases
    f32x4 f[4];
    gemm64(wh1, wl1, xh, xl, bv, lm, l4, pp, f);

    // ---- LN over 64 channels (4-lane butterfly shares pixel pp) ----
    float psum = 0.f, psq = 0.f;
#pragma unroll
    for (int mt = 0; mt < 4; ++mt)
#pragma unroll
        for (int r = 0; r < 4; ++r) { float fv = f[mt][r]; psum += fv; psq += fv * fv; }
    psum += __shfl_xor(psum, 16); psum += __shfl_xor(psum, 32);
    psq  += __shfl_xor(psq, 16);  psq  += __shfl_xor(psq, 32);
    const float m = psum * (1.f / 64.f);
    const float rstd = rsqrtf(psq * (1.f / 64.f) - m * m + EPS_LN);

    float sv_[16];
#pragma unroll
    for (int mt = 0; mt < 4; ++mt)
#pragma unroll
        for (int r = 0; r < 4; ++r) {
            const int o = mt * 16 + l4 * 4 + r;
            float y = bv[64 + o] * (f[mt][r] - m) * rstd + bv[128 + o];
            sv_[mt * 4 + r] = y * sigmoid_f(y);
        }
    __syncthreads();   // conv1 fragment reads complete -> xh/xl reusable
#pragma unroll
    for (int mt = 0; mt < 4; ++mt) {
        uint h0 = pack2(sv_[4 * mt],     sv_[4 * mt + 1]);
        uint h1 = pack2(sv_[4 * mt + 2], sv_[4 * mt + 3]);
        uint l0 = pack2(sv_[4 * mt]     - __uint_as_float((h0 & 0xffffu) << 16),
                        sv_[4 * mt + 1] - __uint_as_float(h0 & 0xffff0000u));
        uint l1 = pack2(sv_[4 * mt + 2] - __uint_as_float((h1 & 0xffffu) << 16),
                        sv_[4 * mt + 3] - __uint_as_float(h1 & 0xffff0000u));
        const int so = pp * 72 + mt * 16 + l4 * 4;
        *(uint2*)&xh[so] = make_uint2(h0, h1);
        *(uint2*)&xl[so] = make_uint2(l0, l1);
    }
    __syncthreads();

    f32x4 z[4];
    gemm64(wh2, wl2, xh, xl, bv + 192, lm, l4, pp, z);

    float sq = 0.f;
#pragma unroll
    for (int mt = 0; mt < 4; ++mt)
#pragma unroll
        for (int r = 0; r < 4; ++r) sq += z[mt][r] * z[mt][r];
    sq += __shfl_xor(sq, 16); sq += __shfl_xor(sq, 32);

    if (pp < 49) {
        const int py = div7s(pp), px = pp - py * 7;
        const int hwi = (ty * 7 + py) * W + tx * 7 + px;
        ushort* dst = &px16[((size_t)b * HW + hwi) * 64];
#pragma unroll
        for (int mt = 0; mt < 4; ++mt)
            *(uint2*)&dst[mt * 16 + l4 * 4] =
                make_uint2(pack2(z[mt][0], z[mt][1]), pack2(z[mt][2], z[mt][3]));
        if (l4 == 0) sqnorm[(size_t)b * HW + hwi] = sq;
    }
}

// ---------------------------------------------------------------------------
// k23: bilateral weights + gated fixup + normalize + neighborhood reduction +
// output_proj. P1-P5 unchanged from r5. P6 (output_proj, 2x 64x64 conv) is
// now split-bf16 MFMA: op weights hi/lo staged into dead haloA strip, P5
// activations written hi/lo into dead haloB strip, LN via 4-lane shfl.
// ---------------------------------------------------------------------------
__global__ __launch_bounds__(256, 2) void k23_fused(
    const ushort* __restrict__ px16, const float* __restrict__ sqnorm,
    const float* __restrict__ sem,  const float* __restrict__ spat,
    const float* __restrict__ fw1, const float* __restrict__ fb1,
    const float* __restrict__ fg,  const float* __restrict__ fbe,
    const float* __restrict__ fw2, const float* __restrict__ fb2,
    const float* __restrict__ w1, const float* __restrict__ b1,
    const float* __restrict__ g,  const float* __restrict__ be,
    const float* __restrict__ w2, const float* __restrict__ b2,
    const float* __restrict__ sigma_, float* __restrict__ out)
{
    __shared__ __align__(16) float smem[18048];          // 72192 B arena
    ushort* haloA = (ushort*)smem;                       // px halo bf16: fl 0..5408
    ushort* haloB = (ushort*)(smem + 5408);              // spat halo bf16: fl 5408..10816
    float*  comb  = smem + 10816;                        // 49x64 -> ..13952
    float*  fscr  = smem + 13952;                        // 49x64 -> ..17088
    float*  sqn_l = smem + 17088;                        // 169   -> ..17257
    float*  pm3   = smem + 17264;                        // 256 (P3 LN partials)
    float*  ps3   = smem + 17520;                        // 256
    float*  pt    = smem + 17776;                        // 256 -> ..18032
    // P3 overlays on dead haloA:
    float*  fwc  = smem;                                 // fx_w1[:, :49] (2401)
    float*  fw2l = smem + 2401;                          // fx_w2 (2401) -> ..4802
    // P6 overlays: w strip over dead haloA (4608 fl = 18432B), act/s strip
    // over dead haloB (4608 fl), bias vec over dead fscr.
    ushort* whiP = (ushort*)smem;                        // [64][72]
    ushort* wloP = (ushort*)smem + 4608;
    ushort* ahiP = (ushort*)(smem + 5408);
    ushort* aloP = (ushort*)(smem + 5408) + 4608;
    float*  bvP  = smem + 13952;                         // 256 floats

    const int tid = threadIdx.x, lane = tid & 63, wv = tid >> 6;
    const int lm = lane & 15, l4 = lane >> 6 == 0 ? (lane >> 4) : 0;  // l4 = lane>>4
    int b, ty, tx; decode_blk(blockIdx.x, b, ty, tx);
    const int lp  = lane < 49 ? lane : 48;
    const int py  = div7s(lp), pxl = lp - py * 7;
    const int h = ty * 7 + py, w = tx * 7 + pxl;
    const int hw = h * W + w;
    const int h0 = ty * 7 - 3, w0 = tx * 7 - 3;
    const bool act = lane < 49;

    // ---- svv prefetch (P3 input): overlaps both stagings ----
    float sv[64];
#pragma unroll
    for (int k = 0; k < 64; ++k) sv[k] = sem[(size_t)(b * 64 + k) * HW + hw];

    // ---- P4 (hoisted): stage spat halo -> haloB (bf16), 1 thread/halo-pix ----
    if (tid < 169) {
        const int ry = div13s(tid), rx = tid - ry * 13;
        const int hh = h0 + ry, ww = w0 + rx;
        const bool valid = (unsigned)hh < (unsigned)H && (unsigned)ww < (unsigned)W;
        const int soff = hh * W + ww;
        const int rsw = (tid & 7), rb_ = tid << 6;
#pragma unroll
        for (int cq = 0; cq < 8; ++cq) {
            uint4 v = make_uint4(0u, 0u, 0u, 0u);
            if (valid) {
                const float* sp = &spat[(size_t)(b * 64 + 8 * cq) * HW + soff];
                v.x = pack2(sp[0],      sp[HW]);
                v.y = pack2(sp[2 * HW], sp[3 * HW]);
                v.z = pack2(sp[4 * HW], sp[5 * HW]);
                v.w = pack2(sp[6 * HW], sp[7 * HW]);
            }
            *(uint4*)&haloB[rb_ + ((cq ^ rsw) << 3)] = v;
        }
    }

    // ---- P1: stage px halo -> haloA (bf16): 1352 16-B loads over 256 thr ----
    for (int i = 0; i < 6; ++i) {
        int idx = i * 256 + tid;
        if (idx < 1352) {
            int r = idx >> 3, q = idx & 7;
            int ry = div13s(r), rx = r - ry * 13;
            int hh = h0 + ry, ww = w0 + rx;
            bool valid = (unsigned)hh < (unsigned)H && (unsigned)ww < (unsigned)W;
            uint4 v = make_uint4(0u, 0u, 0u, 0u);
            if (valid) v = *(const uint4*)&px16[((size_t)b * HW + hh * W + ww) * 64 + 8 * q];
            *(uint4*)&haloA[(r << 6) + ((q ^ (r & 7)) << 3)] = v;
        }
    }
    if (tid < 169) {
        int ry = div13s(tid), rx = tid - ry * 13;
        int hh = h0 + ry, ww = w0 + rx;
        bool valid = (unsigned)hh < (unsigned)H && (unsigned)ww < (unsigned)W;
        float v = 0.f;
        if (valid) v = sqnorm[(size_t)b * HW + hh * W + ww];
        sqn_l[tid] = v;
    }
    __syncthreads();

    // ---- P2: bilateral weights, neighbors split across waves ----
    const int rbase = py * 13 + pxl;
    const int rp = rbase + 42;
    {
        float cv[64];
#pragma unroll
        for (int q = 0; q < 8; ++q) {
            uint4 v = *(const uint4*)&haloA[(rp << 6) + ((q ^ (rp & 7)) << 3)];
            float2 p0_ = up2(v.x), p1_ = up2(v.y), p2_ = up2(v.z), p3_ = up2(v.w);
            cv[8 * q + 0] = p0_.x; cv[8 * q + 1] = p0_.y;
            cv[8 * q + 2] = p1_.x; cv[8 * q + 3] = p1_.y;
            cv[8 * q + 4] = p2_.x; cv[8 * q + 5] = p2_.y;
            cv[8 * q + 6] = p3_.x; cv[8 * q + 7] = p3_.y;
        }
        const float sqc = sqn_l[rp];
        const float sg_ = sigma_[0];
        const float inv2s2 = rcp_fast(2.f * sg_ * sg_);
        for (int i = 0; i < 13; ++i) {
            int n = uni(wv + 4 * i);
            if (n < 49) {
                int ryn = div7s(n), rxn = n - ryn * 7;
                int dy = ryn - 3, dx = rxn - 3;
                int rn = rbase + ryn * 13 + rxn;
                float d0 = 0, d1 = 0, d2 = 0, d3 = 0;
#pragma unroll
                for (int q = 0; q < 8; ++q) {
                    uint4 v = *(const uint4*)&haloA[(rn << 6) + ((q ^ (rn & 7)) << 3)];
                    float2 a = up2(v.x), bb = up2(v.y), c = up2(v.z), d = up2(v.w);
                    d0 += a.x  * cv[8 * q + 0]; d1 += a.y  * cv[8 * q + 1];
                    d2 += bb.x * cv[8 * q + 2]; d3 += bb.y * cv[8 * q + 3];
                    d0 += c.x  * cv[8 * q + 4]; d1 += c.y  * cv[8 * q + 5];
                    d2 += d.x  * cv[8 * q + 6]; d3 += d.y  * cv[8 * q + 7];
                }
                float dot = (d0 + d1) + (d2 + d3);
                float dist2 = fmaxf(sqn_l[rn] + sqc - 2.f * dot, 0.f);
                bool validn = (unsigned)(h + dy) < (unsigned)H && (unsigned)(w + dx) < (unsigned)W;
                float d2n = (float)(dy * dy + dx * dx);
                comb[n * 64 + lane] = validn ? __expf(-(dist2 * (1.f / 128.f) + d2n * inv2s2)) : 0.f;
            }
        }
    }
    __syncthreads();   // px-halo reads + comb writes done (haloA dead below)

    // ---- stage fixup weights into dead haloA region ----
    for (int i = tid; i < 2401; i += 256) {
        int o = div49s(i);
        fwc[i]  = fw1[o * 113 + (i - o * 49)];
        fw2l[i] = fw2[i];
    }
    __syncthreads();

    // ---- P3: gated fixup ----
    float cb[49];
#pragma unroll
    for (int n = 0; n < 49; ++n) cb[n] = comb[n * 64 + lane];
    float macc = 0.f, sacc = 0.f;
    for (int i = 0; i < 13; ++i) {
        const int o = uni(wv + 4 * i);
        if (o < 49) {
            const float* wr = &fwc[o * 49];
            float a0 = 0, a1 = 0, a2 = 0, a3 = 0;
#pragma unroll
            for (int k = 0; k < 48; k += 4) {
                a0 += wr[k] * cb[k];       a1 += wr[k + 1] * cb[k + 1];
                a2 += wr[k + 2] * cb[k + 2]; a3 += wr[k + 3] * cb[k + 3];
            }
            a0 += wr[48] * cb[48];
            const float* wr2 = &fw1[o * 113 + 49];   // sem-half via s_load
#pragma unroll
            for (int k = 0; k < 64; k += 4) {
                a0 += wr2[k] * sv[k];       a1 += wr2[k + 1] * sv[k + 1];
                a2 += wr2[k + 2] * sv[k + 2]; a3 += wr2[k + 3] * sv[k + 3];
            }
            float f = (a0 + a1) + (a2 + a3) + fb1[o];
            fscr[o * 64 + lane] = f;
            macc += f; sacc += f * f;
        }
    }
    pm3[wv * 64 + lane] = macc; ps3[wv * 64 + lane] = sacc;
    __syncthreads();
    {
        float m  = (pm3[lane] + pm3[64 + lane] + pm3[128 + lane] + pm3[192 + lane]) * (1.f / 49.f);
        float va = (ps3[lane] + ps3[64 + lane] + ps3[128 + lane] + ps3[192 + lane]) * (1.f / 49.f) - m * m;
        float rstd = rsqrtf(va + EPS_LN);
        float s[49];
#pragma unroll
        for (int k = 0; k < 49; ++k) {
            float y = fg[k] * (fscr[k * 64 + lane] - m) * rstd + fbe[k];
            s[k] = y * sigmoid_f(y);
        }
        float tacc = 0.f;
        for (int i = 0; i < 13; ++i) {
            const int o = uni(wv + 4 * i);
            if (o < 49) {
                const float* wr = &fw2l[o * 49];
                float a0 = 0, a1 = 0, a2 = 0, a3 = 0;
#pragma unroll
                for (int k = 0; k < 48; k += 4) {
                    a0 += wr[k] * s[k];       a1 += wr[k + 1] * s[k + 1];
                    a2 += wr[k + 2] * s[k + 2]; a3 += wr[k + 3] * s[k + 3];
                }
                a0 += wr[48] * s[48];
                float fo = (a0 + a1) + (a2 + a3) + fb2[o];
                float gate = 1.f + sigmoid_f(fo);
                float cx = comb[o * 64 + lane] * gate;
                comb[o * 64 + lane] = cx;
                tacc += cx;
            }
        }
        pt[wv * 64 + lane] = tacc;
    }
    __syncthreads();
    const float inv = rcp_fast(pt[lane] + pt[64 + lane] + pt[128 + lane] + pt[192 + lane] + EPS_NORM);

    // ---- stage op_w1 (split bf16) into dead haloA strip + bias vec into
    //      dead fscr strip; hides under P5 compute ----
    stage_w(w1, whiP, wloP, tid);
    if (tid < 64) { bvP[tid] = b1[tid]; bvP[64 + tid] = g[tid];
                    bvP[128 + tid] = be[tid]; bvP[192 + tid] = b2[tid]; }

    // ---- P5: weighted neighborhood reduction (haloB, staged at entry) ----
    const int c0 = uni(wv * 16);
    const int qq0 = c0 >> 3;
    float acc[16];
#pragma unroll
    for (int j = 0; j < 16; ++j) acc[j] = 0.f;
    for (int n = 0; n < 49; ++n) {
        int ryn = n / 7, rxn = n - ryn * 7;
        int rn = rbase + ryn * 13 + rxn;
        float cn = comb[n * 64 + lane] * inv;
        const int rb_ = rn << 6, rsw = rn & 7;
#pragma unroll
        for (int q = 0; q < 2; ++q) {
            uint4 v = *(const uint4*)&haloB[rb_ + (((qq0 + q) ^ rsw) << 3)];
            float2 a = up2(v.x), bb = up2(v.y), c = up2(v.z), d = up2(v.w);
            acc[8 * q + 0] += cn * a.x;  acc[8 * q + 1] += cn * a.y;
            acc[8 * q + 2] += cn * bb.x; acc[8 * q + 3] += cn * bb.y;
            acc[8 * q + 4] += cn * c.x;  acc[8 * q + 5] += cn * c.y;
            acc[8 * q + 6] += cn * d.x;  acc[8 * q + 7] += cn * d.y;
        }
    }
    __syncthreads();   // haloB/comb reads done; w1/bias staging visible

    // ---- P6a: write P5 result as split-bf16 activations [pixel][72] ----
    {
        uint hu[8], lu[8];
#pragma unroll
        for (int jj = 0; jj < 8; ++jj) {
            float x0 = act ? acc[2 * jj] : 0.f;
            float x1 = act ? acc[2 * jj + 1] : 0.f;
            uint hh = pack2(x0, x1);
            hu[jj] = hh;
            lu[jj] = pack2(x0 - __uint_as_float((hh & 0xffffu) << 16),
                           x1 - __uint_as_float(hh & 0xffff0000u));
        }
        const int rb = lane * 72 + c0;
        *(uint4*)&ahiP[rb]     = make_uint4(hu[0], hu[1], hu[2], hu[3]);
        *(uint4*)&ahiP[rb + 8] = make_uint4(hu[4], hu[5], hu[6], hu[7]);
        *(uint4*)&aloP[rb]     = make_uint4(lu[0], lu[1], lu[2], lu[3]);
        *(uint4*)&aloP[rb + 8] = make_uint4(lu[4], lu[5], lu[6], lu[7]);
    }
    __syncthreads();

    // ---- P6b: conv1 MFMA + LN(shfl) ----
    const int pp = wv * 16 + lm;
    f32x4 f6[4];
    gemm64(whiP, wloP, ahiP, aloP, bvP, lm, l4, pp, f6);

    float psum = 0.f, psq = 0.f;
#pragma unroll
    for (int mt = 0; mt < 4; ++mt)
#pragma unroll
        for (int r = 0; r < 4; ++r) { float fv = f6[mt][r]; psum += fv; psq += fv * fv; }
    psum += __shfl_xor(psum, 16); psum += __shfl_xor(psum, 32);
    psq  += __shfl_xor(psq, 16);  psq  += __shfl_xor(psq, 32);
    const float m6 = psum * (1.f / 64.f);
    const float rstd6 = rsqrtf(psq * (1.f / 64.f) - m6 * m6 + EPS_LN);

    float yv[16];
#pragma unroll
    for (int mt = 0; mt < 4; ++mt)
#pragma unroll
        for (int r = 0; r < 4; ++r) {
            const int o = mt * 16 + l4 * 4 + r;
            yv[mt * 4 + r] = bvP[64 + o] * (f6[mt][r] - m6) * rstd6 + bvP[128 + o];
        }
    __syncthreads();   // conv1 fragment reads done -> act/w strips reusable

    // write y (split bf16) over act strip; restage op_w2 over w strip
#pragma unroll
    for (int mt = 0; mt < 4; ++mt) {
        uint h0 = pack2(yv[4 * mt],     yv[4 * mt + 1]);
        uint h1 = pack2(yv[4 * mt + 2], yv[4 * mt + 3]);
        uint l0 = pack2(yv[4 * mt]     - __uint_as_float((h0 & 0xffffu) << 16),
                        yv[4 * mt + 1] - __uint_as_float(h0 & 0xffff0000u));
        uint l1 = pack2(yv[4 * mt + 2] - __uint_as_float((h1 & 0xffffu) << 16),
                        yv[4 * mt + 3] - __uint_as_float(h1 & 0xffff0000u));
        const int so = pp * 72 + mt * 16 + l4 * 4;
        *(uint2*)&ahiP[so] = make_uint2(h0, h1);
        *(uint2*)&aloP[so] = make_uint2(l0, l1);
    }
    stage_w(w2, whiP, wloP, tid);
    __syncthreads();

    // ---- P6c: conv2 MFMA + store ----
    f32x4 z6[4];
    gemm64(whiP, wloP, ahiP, aloP, bvP + 192, lm, l4, pp, z6);

    if (pp < 49) {
        const int py6 = div7s(pp), px6 = pp - py6 * 7;
        const int hwi6 = (ty * 7 + py6) * W + tx * 7 + px6;
#pragma unroll
        for (int mt = 0; mt < 4; ++mt)
#pragma unroll
            for (int r = 0; r < 4; ++r)
                out[(size_t)(b * 64 + mt * 16 + l4 * 4 + r) * HW + hwi6] = z6[mt][r];
    }
}

extern "C" void kernel_launch(void* const* d_in, const int* in_sizes, int n_in,
                              void* d_out, int out_size, void* d_ws, size_t ws_size,
                              hipStream_t stream)
{
    const float* spatial  = (const float*)d_in[0];
    const float* semantic = (const float*)d_in[1];
    const float* rp_w1 = (const float*)d_in[2];
    const float* rp_b1 = (const float*)d_in[3];
    const float* rp_g  = (const float*)d_in[4];
    const float* rp_be = (const float*)d_in[5];
    const float* rp_w2 = (const float*)d_in[6];
    const float* rp_b2 = (const float*)d_in[7];
    const float* fx_w1 = (const float*)d_in[8];
    const float* fx_b1 = (const float*)d_in[9];
    const float* fx_g  = (const float*)d_in[10];
    const float* fx_be = (const float*)d_in[11];
    const float* fx_w2 = (const float*)d_in[12];
    const float* fx_b2 = (const float*)d_in[13];
    const float* op_w1 = (const float*)d_in[14];
    const float* op_b1 = (const float*)d_in[15];
    const float* op_g  = (const float*)d_in[16];
    const float* op_be = (const float*)d_in[17];
    const float* op_w2 = (const float*)d_in[18];
    const float* op_b2 = (const float*)d_in[19];
    const float* sigma = (const float*)d_in[20];

    ushort* px16  = (ushort*)d_ws;                              // 3.21 MB
    float* sqnorm = (float*)((char*)d_ws + (size_t)NPIX * 64 * 2);

    k1_range_proj<<<NBLK, 256, 0, stream>>>(
        semantic, rp_w1, rp_b1, rp_g, rp_be, rp_w2, rp_b2, px16, sqnorm);
    k23_fused<<<NBLK, 256, 0, stream>>>(
        px16, sqnorm, semantic, spatial,
        fx_w1, fx_b1, fx_g, fx_be, fx_w2, fx_b2,
        op_w1, op_b1, op_g, op_be, op_w2, op_b2,
        sigma, (float*)d_out);
}

// Round 7
// 155.823 us; speedup vs baseline: 1.2999x; 1.0203x over previous
//
#include <hip/hip_runtime.h>

typedef unsigned short ushort;
typedef unsigned int uint;

constexpr int B = 2, C = 64, H = 112, W = 112;
constexpr int HW = H * W;          // 12544
constexpr int NPIX = B * HW;       // 25088
constexpr int NBLK = 512;          // 2 images x 16x16 tiles of 7x7 -> exactly 2 blocks/CU
constexpr float EPS_LN = 1e-6f, EPS_NORM = 1e-7f;

typedef __attribute__((ext_vector_type(8))) short bf16x8;   // 8 bf16 = 4 VGPRs
typedef __attribute__((ext_vector_type(4))) float f32x4;

__device__ __forceinline__ float rcp_fast(float x) { return __builtin_amdgcn_rcpf(x); }
__device__ __forceinline__ float sigmoid_f(float x) { return rcp_fast(1.f + __expf(-x)); }
__device__ __forceinline__ int uni(int x) { return __builtin_amdgcn_readfirstlane(x); }
__device__ __forceinline__ int div7s(int x)  { return (x * 9363) >> 16; }   // exact for 0<=x<64
__device__ __forceinline__ int div13s(int x) { return (x * 5042) >> 16; }   // exact for 0<=x<169
__device__ __forceinline__ int div49s(int x) { return (x * 1338) >> 16; }   // exact for 0<=x<2520

// f32 -> bf16 bits (round-nearest-even) + pair pack/unpack.
__device__ __forceinline__ ushort rne16(float x) {
    uint u = __float_as_uint(x);
    u += 0x7fffu + ((u >> 16) & 1u);
    return (ushort)(u >> 16);
}
__device__ __forceinline__ uint pack2(float a, float b) {
    return (uint)rne16(a) | ((uint)rne16(b) << 16);
}
__device__ __forceinline__ float2 up2(uint u) {
    return make_float2(__uint_as_float(u << 16), __uint_as_float(u & 0xffff0000u));
}

__device__ __forceinline__ f32x4 mfma16(bf16x8 a, bf16x8 b, f32x4 c) {
    return __builtin_amdgcn_mfma_f32_16x16x32_bf16(a, b, c, 0, 0, 0);
}

// XCD-patch swizzle (BOTH kernels -> producer/consumer share an XCD L2).
__device__ __forceinline__ void decode_blk(int blk, int& b, int& ty, int& tx) {
    int p8 = blk & 7, i = blk >> 3;          // i in [0,64)
    b = p8 >> 2;
    int quad = p8 & 3;
    int lty = i >> 3, ltx = i & 7;           // 8x8 tiles per quadrant
    ty = (quad >> 1) * 8 + lty;              // [0,16)
    tx = (quad & 1) * 8 + ltx;
}

// ---------------------------------------------------------------------------
// Split-bf16 GEMM helpers (see r6). Weights/activations [64][72] bf16 hi/lo.
// ---------------------------------------------------------------------------
__device__ __forceinline__ void stage_w(const float* __restrict__ wsrc,
                                        ushort* wh, ushort* wl, int tid)
{
#pragma unroll
    for (int i = 0; i < 8; ++i) {
        int idx2 = i * 256 + tid;            // 2048 float pairs = 64x64
        int o = idx2 >> 5, k = (idx2 & 31) * 2;
        float2 xy = *(const float2*)&wsrc[o * 64 + k];
        uint h = pack2(xy.x, xy.y);
        *(uint*)&wh[o * 72 + k] = h;
        *(uint*)&wl[o * 72 + k] = pack2(xy.x - __uint_as_float((h & 0xffffu) << 16),
                                        xy.y - __uint_as_float(h & 0xffff0000u));
    }
}

__device__ __forceinline__ void gemm64(const ushort* __restrict__ wh, const ushort* __restrict__ wl,
                                       const ushort* __restrict__ xh, const ushort* __restrict__ xl,
                                       const float* __restrict__ bias,
                                       int lm, int l4, int pp, f32x4 acc[4])
{
#pragma unroll
    for (int mt = 0; mt < 4; ++mt) {
        const int ob = mt * 16 + l4 * 4;
        acc[mt][0] = bias[ob]; acc[mt][1] = bias[ob + 1];
        acc[mt][2] = bias[ob + 2]; acc[mt][3] = bias[ob + 3];
    }
#pragma unroll
    for (int kt = 0; kt < 2; ++kt) {
        const int xo = pp * 72 + kt * 32 + l4 * 8;
        bf16x8 bh = *(const bf16x8*)&xh[xo];
        bf16x8 bl = *(const bf16x8*)&xl[xo];
#pragma unroll
        for (int mt = 0; mt < 4; ++mt) {
            const int wo = (mt * 16 + lm) * 72 + kt * 32 + l4 * 8;
            bf16x8 ah = *(const bf16x8*)&wh[wo];
            bf16x8 al = *(const bf16x8*)&wl[wo];
            acc[mt] = mfma16(al, bh, acc[mt]);
            acc[mt] = mfma16(ah, bl, acc[mt]);
            acc[mt] = mfma16(ah, bh, acc[mt]);
        }
    }
}

// ---------------------------------------------------------------------------
// k1: px = range_proj(semantic) -> px16[p][64] (bf16) + sqnorm[p].
// Unchanged from r6 (full split-bf16 MFMA; verified).
// ---------------------------------------------------------------------------
__global__ __launch_bounds__(256) void k1_range_proj(
    const float* __restrict__ sem,
    const float* __restrict__ w1, const float* __restrict__ b1,
    const float* __restrict__ g,  const float* __restrict__ be,
    const float* __restrict__ w2, const float* __restrict__ b2,
    ushort* __restrict__ px16, float* __restrict__ sqnorm)
{
    __shared__ __align__(16) ushort u16[28160];   // 56320 B
    ushort* wh1 = u16;                 // [64][72] each (4608 ushorts)
    ushort* wl1 = u16 + 4608;
    ushort* wh2 = u16 + 9216;
    ushort* wl2 = u16 + 13824;
    ushort* xh  = u16 + 18432;         // activations / s (reused)
    ushort* xl  = u16 + 23040;         // ..27648
    float*  bv  = (float*)(u16 + 27648);   // b1|g|be|b2 (256 floats)

    const int tid = threadIdx.x, lane = tid & 63, wv = tid >> 6;
    const int lm = lane & 15, l4 = lane >> 4;
    int b, ty, tx; decode_blk(blockIdx.x, b, ty, tx);

    // ---- stage activations: wave wv loads channels [wv*16,+16) of pixel=lane
    {
        const int lp = lane < 49 ? lane : 48;
        const int py = div7s(lp), px = lp - py * 7;
        const int hw = (ty * 7 + py) * W + tx * 7 + px;
        const bool a = lane < 49;
        float xv[16];
#pragma unroll
        for (int j = 0; j < 16; ++j)
            xv[j] = a ? sem[(size_t)(b * 64 + wv * 16 + j) * HW + hw] : 0.f;
        uint hu[8], lu[8];
#pragma unroll
        for (int jj = 0; jj < 8; ++jj) {
            uint hh = pack2(xv[2 * jj], xv[2 * jj + 1]);
            hu[jj] = hh;
            lu[jj] = pack2(xv[2 * jj]     - __uint_as_float((hh & 0xffffu) << 16),
                           xv[2 * jj + 1] - __uint_as_float(hh & 0xffff0000u));
        }
        const int rb = lane * 72 + wv * 16;
        *(uint4*)&xh[rb]     = make_uint4(hu[0], hu[1], hu[2], hu[3]);
        *(uint4*)&xh[rb + 8] = make_uint4(hu[4], hu[5], hu[6], hu[7]);
        *(uint4*)&xl[rb]     = make_uint4(lu[0], lu[1], lu[2], lu[3]);
        *(uint4*)&xl[rb + 8] = make_uint4(lu[4], lu[5], lu[6], lu[7]);
    }
    stage_w(w1, wh1, wl1, tid);
    stage_w(w2, wh2, wl2, tid);
    if (tid < 64) { bv[tid] = b1[tid]; bv[64 + tid] = g[tid];
                    bv[128 + tid] = be[tid]; bv[192 + tid] = b2[tid]; }
    __syncthreads();

    const int pp = wv * 16 + lm;       // this lane's pixel for MFMA phases
    f32x4 f[4];
    gemm64(wh1, wl1, xh, xl, bv, lm, l4, pp, f);

    // ---- LN over 64 channels (4-lane butterfly shares pixel pp) ----
    float psum = 0.f, psq = 0.f;
#pragma unroll
    for (int mt = 0; mt < 4; ++mt)
#pragma unroll
        for (int r = 0; r < 4; ++r) { float fv = f[mt][r]; psum += fv; psq += fv * fv; }
    psum += __shfl_xor(psum, 16); psum += __shfl_xor(psum, 32);
    psq  += __shfl_xor(psq, 16);  psq  += __shfl_xor(psq, 32);
    const float m = psum * (1.f / 64.f);
    const float rstd = rsqrtf(psq * (1.f / 64.f) - m * m + EPS_LN);

    float sv_[16];
#pragma unroll
    for (int mt = 0; mt < 4; ++mt)
#pragma unroll
        for (int r = 0; r < 4; ++r) {
            const int o = mt * 16 + l4 * 4 + r;
            float y = bv[64 + o] * (f[mt][r] - m) * rstd + bv[128 + o];
            sv_[mt * 4 + r] = y * sigmoid_f(y);
        }
    __syncthreads();   // conv1 fragment reads complete -> xh/xl reusable
#pragma unroll
    for (int mt = 0; mt < 4; ++mt) {
        uint h0 = pack2(sv_[4 * mt],     sv_[4 * mt + 1]);
        uint h1 = pack2(sv_[4 * mt + 2], sv_[4 * mt + 3]);
        uint l0 = pack2(sv_[4 * mt]     - __uint_as_float((h0 & 0xffffu) << 16),
                        sv_[4 * mt + 1] - __uint_as_float(h0 & 0xffff0000u));
        uint l1 = pack2(sv_[4 * mt + 2] - __uint_as_float((h1 & 0xffffu) << 16),
                        sv_[4 * mt + 3] - __uint_as_float(h1 & 0xffff0000u));
        const int so = pp * 72 + mt * 16 + l4 * 4;
        *(uint2*)&xh[so] = make_uint2(h0, h1);
        *(uint2*)&xl[so] = make_uint2(l0, l1);
    }
    __syncthreads();

    f32x4 z[4];
    gemm64(wh2, wl2, xh, xl, bv + 192, lm, l4, pp, z);

    float sq = 0.f;
#pragma unroll
    for (int mt = 0; mt < 4; ++mt)
#pragma unroll
        for (int r = 0; r < 4; ++r) sq += z[mt][r] * z[mt][r];
    sq += __shfl_xor(sq, 16); sq += __shfl_xor(sq, 32);

    if (pp < 49) {
        const int py = div7s(pp), px = pp - py * 7;
        const int hwi = (ty * 7 + py) * W + tx * 7 + px;
        ushort* dst = &px16[((size_t)b * HW + hwi) * 64];
#pragma unroll
        for (int mt = 0; mt < 4; ++mt)
            *(uint2*)&dst[mt * 16 + l4 * 4] =
                make_uint2(pack2(z[mt][0], z[mt][1]), pack2(z[mt][2], z[mt][3]));
        if (l4 == 0) sqnorm[(size_t)b * HW + hwi] = sq;
    }
}

// ---------------------------------------------------------------------------
// k23 (r7): P2 dot products now MFMA. haloA [169][64] bf16 is ALREADY in
// A/B-fragment layout -> compute the full cross-dot matrix D[hp][p] (bf16
// MFMA, products exact, no split) into dmat (f32 [176][66]) overlaid on the
// dead haloB/comb/fscr strip; extraction = 13 LDS reads + exp per wave.
// haloB staging moves post-extraction (HBM latency hides under P3).
// P3/P5/P6 unchanged from r6.
// ---------------------------------------------------------------------------
__global__ __launch_bounds__(256, 2) void k23_fused(
    const ushort* __restrict__ px16, const float* __restrict__ sqnorm,
    const float* __restrict__ sem,  const float* __restrict__ spat,
    const float* __restrict__ fw1, const float* __restrict__ fb1,
    const float* __restrict__ fg,  const float* __restrict__ fbe,
    const float* __restrict__ fw2, const float* __restrict__ fb2,
    const float* __restrict__ w1, const float* __restrict__ b1,
    const float* __restrict__ g,  const float* __restrict__ be,
    const float* __restrict__ w2, const float* __restrict__ b2,
    const float* __restrict__ sigma_, float* __restrict__ out)
{
    __shared__ __align__(16) float smem[18048];          // 72192 B arena
    ushort* haloA = (ushort*)smem;                       // px halo bf16: fl 0..5408
    ushort* haloB = (ushort*)(smem + 5408);              // spat halo bf16 (staged post-P2)
    float*  comb  = smem + 10816;                        // 49x64 -> ..13952
    float*  fscr  = smem + 13952;                        // 49x64 -> ..17088
    float*  sqn_l = smem + 17088;                        // 169   -> ..17257
    float*  pm3   = smem + 17264;                        // 256
    float*  ps3   = smem + 17520;                        // 256
    float*  pt    = smem + 17776;                        // 256 -> ..18032
    // P2 overlay: D matrix f32 [176][66] over haloB+comb+fscr strip
    float*  dmat  = smem + 5408;                         // [5408, 17024)
    // P3 overlays on dead haloA:
    float*  fwc  = smem;                                 // fx_w1[:, :49] (2401)
    float*  fw2l = smem + 2401;                          // fx_w2 (2401) -> ..4802
    // P6 overlays (as r6):
    ushort* whiP = (ushort*)smem;                        // [64][72]
    ushort* wloP = (ushort*)smem + 4608;
    ushort* ahiP = (ushort*)(smem + 5408);
    ushort* aloP = (ushort*)(smem + 5408) + 4608;
    float*  bvP  = smem + 13952;                         // 256 floats

    const int tid = threadIdx.x, lane = tid & 63, wv = tid >> 6;
    const int lm = lane & 15, l4 = lane >> 4;
    int b, ty, tx; decode_blk(blockIdx.x, b, ty, tx);
    const int lp  = lane < 49 ? lane : 48;
    const int py  = div7s(lp), pxl = lp - py * 7;
    const int h = ty * 7 + py, w = tx * 7 + pxl;
    const int hw = h * W + w;
    const int h0 = ty * 7 - 3, w0 = tx * 7 - 3;
    const bool act = lane < 49;

    // ---- sv prefetch (P3 input) ----
    float sv[64];
#pragma unroll
    for (int k = 0; k < 64; ++k) sv[k] = sem[(size_t)(b * 64 + k) * HW + hw];

    // ---- P1: stage px halo -> haloA (bf16): 1352 16-B loads over 256 thr ----
    for (int i = 0; i < 6; ++i) {
        int idx = i * 256 + tid;
        if (idx < 1352) {
            int r = idx >> 3, q = idx & 7;
            int ry = div13s(r), rx = r - ry * 13;
            int hh = h0 + ry, ww = w0 + rx;
            bool valid = (unsigned)hh < (unsigned)H && (unsigned)ww < (unsigned)W;
            uint4 v = make_uint4(0u, 0u, 0u, 0u);
            if (valid) v = *(const uint4*)&px16[((size_t)b * HW + hh * W + ww) * 64 + 8 * q];
            *(uint4*)&haloA[(r << 6) + ((q ^ (r & 7)) << 3)] = v;
        }
    }
    if (tid < 169) {
        int ry = div13s(tid), rx = tid - ry * 13;
        int hh = h0 + ry, ww = w0 + rx;
        bool valid = (unsigned)hh < (unsigned)H && (unsigned)ww < (unsigned)W;
        float v = 0.f;
        if (valid) v = sqnorm[(size_t)b * HW + hh * W + ww];
        sqn_l[tid] = v;
    }
    __syncthreads();

    // ---- P2-MFMA: D[hp][p] = <haloA[hp], haloA[rp(p)]>, all 169(+7) x 64 ----
    {
        const int pp2 = wv * 16 + lm;
        const int qp = pp2 < 49 ? pp2 : 48;
        const int pyp = div7s(qp), pxp = qp - pyp * 7;
        const int rpp = pyp * 13 + pxp + 42;
        bf16x8 bc0 = *(const bf16x8*)&haloA[(rpp << 6) + ((l4 ^ (rpp & 7)) << 3)];
        bf16x8 bc1 = *(const bf16x8*)&haloA[(rpp << 6) + (((4 + l4) ^ (rpp & 7)) << 3)];
#pragma unroll
        for (int mt = 0; mt < 11; ++mt) {
            const int r = mt * 16 + lm;
            bf16x8 a0 = *(const bf16x8*)&haloA[(r << 6) + ((l4 ^ (r & 7)) << 3)];
            bf16x8 a1 = *(const bf16x8*)&haloA[(r << 6) + (((4 + l4) ^ (r & 7)) << 3)];
            f32x4 d = {0.f, 0.f, 0.f, 0.f};
            d = mfma16(a0, bc0, d);
            d = mfma16(a1, bc1, d);
            const int orow = mt * 16 + l4 * 4;
#pragma unroll
            for (int rr = 0; rr < 4; ++rr)
                dmat[(orow + rr) * 66 + pp2] = d[rr];
        }
    }
    __syncthreads();

    // ---- extraction (wave-split n) into regs; fixup weights -> dead haloA ----
    const int rbase = py * 13 + pxl;
    const int rp = rbase + 42;
    float cbl[13];
    {
        const float sqc = sqn_l[rp];
        const float sg_ = sigma_[0];
        const float inv2s2 = rcp_fast(2.f * sg_ * sg_);
#pragma unroll
        for (int i = 0; i < 13; ++i) {
            const int n = uni(wv + 4 * i);
            cbl[i] = 0.f;
            if (n < 49) {
                int ryn = div7s(n), rxn = n - ryn * 7;
                int dy = ryn - 3, dx = rxn - 3;
                int rn = rbase + ryn * 13 + rxn;
                float dot = dmat[rn * 66 + lane];
                float dist2 = fmaxf(sqn_l[rn] + sqc - 2.f * dot, 0.f);
                bool validn = (unsigned)(h + dy) < (unsigned)H && (unsigned)(w + dx) < (unsigned)W;
                float d2n = (float)(dy * dy + dx * dx);
                cbl[i] = validn ? __expf(-(dist2 * (1.f / 128.f) + d2n * inv2s2)) : 0.f;
            }
        }
    }
    for (int i = tid; i < 2401; i += 256) {       // disjoint from dmat reads
        int o = div49s(i);
        fwc[i]  = fw1[o * 113 + (i - o * 49)];
        fw2l[i] = fw2[i];
    }
    __syncthreads();   // dmat dead below

    // ---- write comb + stage spat halo -> haloB (over dead dmat region) ----
#pragma unroll
    for (int i = 0; i < 13; ++i) {
        const int n = wv + 4 * i;
        if (n < 49) comb[n * 64 + lane] = cbl[i];
    }
    if (tid < 169) {
        const int ry = div13s(tid), rx = tid - ry * 13;
        const int hh = h0 + ry, ww = w0 + rx;
        const bool valid = (unsigned)hh < (unsigned)H && (unsigned)ww < (unsigned)W;
        const int soff = hh * W + ww;
        const int rsw = (tid & 7), rb_ = tid << 6;
#pragma unroll
        for (int cq = 0; cq < 8; ++cq) {
            uint4 v = make_uint4(0u, 0u, 0u, 0u);
            if (valid) {
                const float* sp = &spat[(size_t)(b * 64 + 8 * cq) * HW + soff];
                v.x = pack2(sp[0],      sp[HW]);
                v.y = pack2(sp[2 * HW], sp[3 * HW]);
                v.z = pack2(sp[4 * HW], sp[5 * HW]);
                v.w = pack2(sp[6 * HW], sp[7 * HW]);
            }
            *(uint4*)&haloB[rb_ + ((cq ^ rsw) << 3)] = v;
        }
    }
    __syncthreads();

    // ---- P3: gated fixup (unchanged from r6) ----
    float cb[49];
#pragma unroll
    for (int n = 0; n < 49; ++n) cb[n] = comb[n * 64 + lane];
    float macc = 0.f, sacc = 0.f;
    for (int i = 0; i < 13; ++i) {
        const int o = uni(wv + 4 * i);
        if (o < 49) {
            const float* wr = &fwc[o * 49];
            float a0 = 0, a1 = 0, a2 = 0, a3 = 0;
#pragma unroll
            for (int k = 0; k < 48; k += 4) {
                a0 += wr[k] * cb[k];       a1 += wr[k + 1] * cb[k + 1];
                a2 += wr[k + 2] * cb[k + 2]; a3 += wr[k + 3] * cb[k + 3];
            }
            a0 += wr[48] * cb[48];
            const float* wr2 = &fw1[o * 113 + 49];   // sem-half via s_load
#pragma unroll
            for (int k = 0; k < 64; k += 4) {
                a0 += wr2[k] * sv[k];       a1 += wr2[k + 1] * sv[k + 1];
                a2 += wr2[k + 2] * sv[k + 2]; a3 += wr2[k + 3] * sv[k + 3];
            }
            float f = (a0 + a1) + (a2 + a3) + fb1[o];
            fscr[o * 64 + lane] = f;
            macc += f; sacc += f * f;
        }
    }
    pm3[wv * 64 + lane] = macc; ps3[wv * 64 + lane] = sacc;
    __syncthreads();
    {
        float m  = (pm3[lane] + pm3[64 + lane] + pm3[128 + lane] + pm3[192 + lane]) * (1.f / 49.f);
        float va = (ps3[lane] + ps3[64 + lane] + ps3[128 + lane] + ps3[192 + lane]) * (1.f / 49.f) - m * m;
        float rstd = rsqrtf(va + EPS_LN);
        float s[49];
#pragma unroll
        for (int k = 0; k < 49; ++k) {
            float y = fg[k] * (fscr[k * 64 + lane] - m) * rstd + fbe[k];
            s[k] = y * sigmoid_f(y);
        }
        float tacc = 0.f;
        for (int i = 0; i < 13; ++i) {
            const int o = uni(wv + 4 * i);
            if (o < 49) {
                const float* wr = &fw2l[o * 49];
                float a0 = 0, a1 = 0, a2 = 0, a3 = 0;
#pragma unroll
                for (int k = 0; k < 48; k += 4) {
                    a0 += wr[k] * s[k];       a1 += wr[k + 1] * s[k + 1];
                    a2 += wr[k + 2] * s[k + 2]; a3 += wr[k + 3] * s[k + 3];
                }
                a0 += wr[48] * s[48];
                float fo = (a0 + a1) + (a2 + a3) + fb2[o];
                float gate = 1.f + sigmoid_f(fo);
                float cx = comb[o * 64 + lane] * gate;
                comb[o * 64 + lane] = cx;
                tacc += cx;
            }
        }
        pt[wv * 64 + lane] = tacc;
    }
    __syncthreads();
    const float inv = rcp_fast(pt[lane] + pt[64 + lane] + pt[128 + lane] + pt[192 + lane] + EPS_NORM);

    // ---- stage op_w1 (split bf16) + bias vec; hides under P5 compute ----
    stage_w(w1, whiP, wloP, tid);
    if (tid < 64) { bvP[tid] = b1[tid]; bvP[64 + tid] = g[tid];
                    bvP[128 + tid] = be[tid]; bvP[192 + tid] = b2[tid]; }

    // ---- P5: weighted neighborhood reduction (haloB) ----
    const int c0 = uni(wv * 16);
    const int qq0 = c0 >> 3;
    float acc[16];
#pragma unroll
    for (int j = 0; j < 16; ++j) acc[j] = 0.f;
    for (int n = 0; n < 49; ++n) {
        int ryn = n / 7, rxn = n - ryn * 7;
        int rn = rbase + ryn * 13 + rxn;
        float cn = comb[n * 64 + lane] * inv;
        const int rb_ = rn << 6, rsw = rn & 7;
#pragma unroll
        for (int q = 0; q < 2; ++q) {
            uint4 v = *(const uint4*)&haloB[rb_ + (((qq0 + q) ^ rsw) << 3)];
            float2 a = up2(v.x), bb = up2(v.y), c = up2(v.z), d = up2(v.w);
            acc[8 * q + 0] += cn * a.x;  acc[8 * q + 1] += cn * a.y;
            acc[8 * q + 2] += cn * bb.x; acc[8 * q + 3] += cn * bb.y;
            acc[8 * q + 4] += cn * c.x;  acc[8 * q + 5] += cn * c.y;
            acc[8 * q + 6] += cn * d.x;  acc[8 * q + 7] += cn * d.y;
        }
    }
    __syncthreads();   // haloB/comb reads done; w1/bias staging visible

    // ---- P6a: write P5 result as split-bf16 activations [pixel][72] ----
    {
        uint hu[8], lu[8];
#pragma unroll
        for (int jj = 0; jj < 8; ++jj) {
            float x0 = act ? acc[2 * jj] : 0.f;
            float x1 = act ? acc[2 * jj + 1] : 0.f;
            uint hh = pack2(x0, x1);
            hu[jj] = hh;
            lu[jj] = pack2(x0 - __uint_as_float((hh & 0xffffu) << 16),
                           x1 - __uint_as_float(hh & 0xffff0000u));
        }
        const int rb = lane * 72 + c0;
        *(uint4*)&ahiP[rb]     = make_uint4(hu[0], hu[1], hu[2], hu[3]);
        *(uint4*)&ahiP[rb + 8] = make_uint4(hu[4], hu[5], hu[6], hu[7]);
        *(uint4*)&aloP[rb]     = make_uint4(lu[0], lu[1], lu[2], lu[3]);
        *(uint4*)&aloP[rb + 8] = make_uint4(lu[4], lu[5], lu[6], lu[7]);
    }
    __syncthreads();

    // ---- P6b: conv1 MFMA + LN(shfl) ----
    const int pp = wv * 16 + lm;
    f32x4 f6[4];
    gemm64(whiP, wloP, ahiP, aloP, bvP, lm, l4, pp, f6);

    float psum = 0.f, psq = 0.f;
#pragma unroll
    for (int mt = 0; mt < 4; ++mt)
#pragma unroll
        for (int r = 0; r < 4; ++r) { float fv = f6[mt][r]; psum += fv; psq += fv * fv; }
    psum += __shfl_xor(psum, 16); psum += __shfl_xor(psum, 32);
    psq  += __shfl_xor(psq, 16);  psq  += __shfl_xor(psq, 32);
    const float m6 = psum * (1.f / 64.f);
    const float rstd6 = rsqrtf(psq * (1.f / 64.f) - m6 * m6 + EPS_LN);

    float yv[16];
#pragma unroll
    for (int mt = 0; mt < 4; ++mt)
#pragma unroll
        for (int r = 0; r < 4; ++r) {
            const int o = mt * 16 + l4 * 4 + r;
            yv[mt * 4 + r] = bvP[64 + o] * (f6[mt][r] - m6) * rstd6 + bvP[128 + o];
        }
    __syncthreads();   // conv1 fragment reads done -> act/w strips reusable

    // write y (split bf16) over act strip; restage op_w2 over w strip
#pragma unroll
    for (int mt = 0; mt < 4; ++mt) {
        uint h0 = pack2(yv[4 * mt],     yv[4 * mt + 1]);
        uint h1 = pack2(yv[4 * mt + 2], yv[4 * mt + 3]);
        uint l0 = pack2(yv[4 * mt]     - __uint_as_float((h0 & 0xffffu) << 16),
                        yv[4 * mt + 1] - __uint_as_float(h0 & 0xffff0000u));
        uint l1 = pack2(yv[4 * mt + 2] - __uint_as_float((h1 & 0xffffu) << 16),
                        yv[4 * mt + 3] - __uint_as_float(h1 & 0xffff0000u));
        const int so = pp * 72 + mt * 16 + l4 * 4;
        *(uint2*)&ahiP[so] = make_uint2(h0, h1);
        *(uint2*)&aloP[so] = make_uint2(l0, l1);
    }
    stage_w(w2, whiP, wloP, tid);
    __syncthreads();

    // ---- P6c: conv2 MFMA + store ----
    f32x4 z6[4];
    gemm64(whiP, wloP, ahiP, aloP, bvP + 192, lm, l4, pp, z6);

    if (pp < 49) {
        const int py6 = div7s(pp), px6 = pp - py6 * 7;
        const int hwi6 = (ty * 7 + py6) * W + tx * 7 + px6;
#pragma unroll
        for (int mt = 0; mt < 4; ++mt)
#pragma unroll
            for (int r = 0; r < 4; ++r)
                out[(size_t)(b * 64 + mt * 16 + l4 * 4 + r) * HW + hwi6] = z6[mt][r];
    }
}

extern "C" void kernel_launch(void* const* d_in, const int* in_sizes, int n_in,
                              void* d_out, int out_size, void* d_ws, size_t ws_size,
                              hipStream_t stream)
{
    const float* spatial  = (const float*)d_in[0];
    const float* semantic = (const float*)d_in[1];
    const float* rp_w1 = (const float*)d_in[2];
    const float* rp_b1 = (const float*)d_in[3];
    const float* rp_g  = (const float*)d_in[4];
    const float* rp_be = (const float*)d_in[5];
    const float* rp_w2 = (const float*)d_in[6];
    const float* rp_b2 = (const float*)d_in[7];
    const float* fx_w1 = (const float*)d_in[8];
    const float* fx_b1 = (const float*)d_in[9];
    const float* fx_g  = (const float*)d_in[10];
    const float* fx_be = (const float*)d_in[11];
    const float* fx_w2 = (const float*)d_in[12];
    const float* fx_b2 = (const float*)d_in[13];
    const float* op_w1 = (const float*)d_in[14];
    const float* op_b1 = (const float*)d_in[15];
    const float* op_g  = (const float*)d_in[16];
    const float* op_be = (const float*)d_in[17];
    const float* op_w2 = (const float*)d_in[18];
    const float* op_b2 = (const float*)d_in[19];
    const float* sigma = (const float*)d_in[20];

    ushort* px16  = (ushort*)d_ws;                              // 3.21 MB
    float* sqnorm = (float*)((char*)d_ws + (size_t)NPIX * 64 * 2);

    k1_range_proj<<<NBLK, 256, 0, stream>>>(
        semantic, rp_w1, rp_b1, rp_g, rp_be, rp_w2, rp_b2, px16, sqnorm);
    k23_fused<<<NBLK, 256, 0, stream>>>(
        px16, sqnorm, semantic, spatial,
        fx_w1, fx_b1, fx_g, fx_be, fx_w2, fx_b2,
        op_w1, op_b1, op_g, op_be, op_w2, op_b2,
        sigma, (float*)d_out);
}